// Round 1
// baseline (1307.850 us; speedup 1.0000x reference)
//
#include <hip/hip_runtime.h>
#include <hip/hip_bf16.h>

// TimeMoERouter: B=8 S=512 H=1024 E=8 TOPK=2 NHEADS=8 DH=128 CAP=1536
// T = B*S = 4096 tokens.
// Round 1: full-fp32 baseline. All matmuls via one tiled VALU GEMM kernel.
// d_out (402MB) doubles as scratch arena; zero-fill runs after compute.

#define Tt 4096
#define Hh 1024
#define Ss 512
#define Ee 8
#define CAPc 1536
#define NH 8
#define DH 128

// ---------------- GEMM ----------------
// C[m,n] = alpha * sum_k A[m,k] * B'[.,.] (+ biasN[n]) (+ biasSN[m%smod, n]) (relu?)
// TRANSB=false: B is W[N,K] row-major (torch Linear) -> C = A*W^T
// TRANSB=true : B is [K,N] row-major               -> C = A*B
// Batched via blockIdx.z: zj=z/zdiv, zi=z%zdiv; ptr += zj*sMaj + zi*sMin.
#define TILE 128
#define BKk 8

template<bool TRANSB, bool RELU, bool HAS_BN, bool HAS_BSN>
__global__ __launch_bounds__(256) void gemm_k(
    const float* __restrict__ A, int lda, long long sAmaj, long long sAmin,
    const float* __restrict__ B, int ldb, long long sBmaj, long long sBmin,
    float* __restrict__ C, int ldc, long long sCmaj, long long sCmin,
    int Kd, int zdiv,
    const float* __restrict__ bN,
    const float* __restrict__ bSN, int ldbs, int smod,
    float alpha)
{
  int z = blockIdx.z;
  int zj = z / zdiv, zi = z - zj * zdiv;
  A += (size_t)zj * sAmaj + (size_t)zi * sAmin;
  B += (size_t)zj * sBmaj + (size_t)zi * sBmin;
  C += (size_t)zj * sCmaj + (size_t)zi * sCmin;

  int m0 = blockIdx.y * TILE, n0 = blockIdx.x * TILE;
  __shared__ float As[BKk][TILE];
  __shared__ float Bs[BKk][TILE];

  int t = threadIdx.x;
  int tx = t & 15, ty = t >> 4;

  float acc[8][8];
#pragma unroll
  for (int i = 0; i < 8; ++i)
#pragma unroll
    for (int j = 0; j < 8; ++j) acc[i][j] = 0.f;

  int lr = t >> 1;            // 0..127
  int lh = (t & 1) * 4;       // 0 or 4
  int bkr = t >> 5;           // 0..7   (TRANSB load)
  int bcg = (t & 31) * 4;     // 0..124 (TRANSB load)

  for (int k0 = 0; k0 < Kd; k0 += BKk) {
    __syncthreads();
    {
      const float* pa = A + (size_t)(m0 + lr) * lda + k0 + lh;
      float2 a0 = *(const float2*)pa;
      float2 a1 = *(const float2*)(pa + 2);
      As[lh + 0][lr] = a0.x; As[lh + 1][lr] = a0.y;
      As[lh + 2][lr] = a1.x; As[lh + 3][lr] = a1.y;
    }
    if (!TRANSB) {
      const float* pb = B + (size_t)(n0 + lr) * ldb + k0 + lh;
      float2 b0 = *(const float2*)pb;
      float2 b1 = *(const float2*)(pb + 2);
      Bs[lh + 0][lr] = b0.x; Bs[lh + 1][lr] = b0.y;
      Bs[lh + 2][lr] = b1.x; Bs[lh + 3][lr] = b1.y;
    } else {
      const float* pb = B + (size_t)(k0 + bkr) * ldb + n0 + bcg;
      float2 b0 = *(const float2*)pb;
      float2 b1 = *(const float2*)(pb + 2);
      *(float4*)&Bs[bkr][bcg] = make_float4(b0.x, b0.y, b1.x, b1.y);
    }
    __syncthreads();
#pragma unroll
    for (int kk = 0; kk < BKk; ++kk) {
      float a[8], b[8];
      *(float4*)&a[0] = *(const float4*)&As[kk][ty * 8];
      *(float4*)&a[4] = *(const float4*)&As[kk][ty * 8 + 4];
      *(float4*)&b[0] = *(const float4*)&Bs[kk][tx * 8];
      *(float4*)&b[4] = *(const float4*)&Bs[kk][tx * 8 + 4];
#pragma unroll
      for (int i = 0; i < 8; ++i)
#pragma unroll
        for (int j = 0; j < 8; ++j) acc[i][j] += a[i] * b[j];
    }
  }

#pragma unroll
  for (int i = 0; i < 8; ++i) {
    int m = m0 + ty * 8 + i;
    float v[8];
#pragma unroll
    for (int j = 0; j < 8; ++j) {
      int n = n0 + tx * 8 + j;
      float x = acc[i][j] * alpha;
      if (HAS_BN) x += bN[n];
      if (HAS_BSN) x += bSN[(size_t)(m % smod) * ldbs + n];
      if (RELU) x = fmaxf(x, 0.f);
      v[j] = x;
    }
    float* cp = C + (size_t)m * ldc + n0 + tx * 8;
    *(float4*)cp = make_float4(v[0], v[1], v[2], v[3]);
    *(float4*)(cp + 4) = make_float4(v[4], v[5], v[6], v[7]);
  }
}

// ---------------- seasonal / positional precompute ----------------
// per s: se path (scalar -> 256 -> 256 -> 1024), plus bias1 folding te_b1 +
// ts*w[:,1024] + se*w[:,1025]. Grid 512 blocks x 256 threads.
__global__ __launch_bounds__(256) void precompute_k(
    const float* __restrict__ pos_emb,
    const float* __restrict__ se_w1, const float* __restrict__ se_b1,
    const float* __restrict__ se_w2, const float* __restrict__ se_b2,
    const float* __restrict__ sexp_w, const float* __restrict__ sexp_b,
    const float* __restrict__ te_w1, const float* __restrict__ te_b1,
    float* __restrict__ psea, float* __restrict__ bias1)
{
  int s = blockIdx.x, t = threadIdx.x;
  float ts = (float)s;
  float se = sinf(((ts * 2.0f) * 3.14159274101257324f) / 24.0f);
  __shared__ float l1[256], l2[256];
  l1[t] = fmaxf(se * se_w1[t] + se_b1[t], 0.f);
  __syncthreads();
  {
    float a = se_b2[t];
    const float* wr = se_w2 + (size_t)t * 256;
    for (int i = 0; i < 256; ++i) a += l1[i] * wr[i];
    l2[t] = a;
  }
  __syncthreads();
#pragma unroll
  for (int r = 0; r < 4; ++r) {
    int h = r * 256 + t;
    float v = sexp_b[h];
    const float* wr = sexp_w + (size_t)h * 256;
    for (int j = 0; j < 256; ++j) v += l2[j] * wr[j];
    psea[s * Hh + h] = pos_emb[s * Hh + h] + v;
    bias1[s * Hh + h] = te_b1[h] + ts * te_w1[(size_t)h * 1026 + 1024]
                                 + se * te_w1[(size_t)h * 1026 + 1025];
  }
}

// ---------------- attention row softmax ----------------
// scores: [64, 512, 512]; one wave per row, 4 rows per block.
__global__ __launch_bounds__(256) void softmax_k(float* __restrict__ S)
{
  int row = blockIdx.x * 4 + (threadIdx.x >> 6);
  int lane = threadIdx.x & 63;
  float* p = S + (size_t)row * 512;
  float4 a = *(float4*)&p[lane * 4];
  float4 b = *(float4*)&p[256 + lane * 4];
  float m = fmaxf(fmaxf(fmaxf(a.x, a.y), fmaxf(a.z, a.w)),
                  fmaxf(fmaxf(b.x, b.y), fmaxf(b.z, b.w)));
#pragma unroll
  for (int off = 32; off; off >>= 1) m = fmaxf(m, __shfl_xor(m, off));
  a.x = expf(a.x - m); a.y = expf(a.y - m); a.z = expf(a.z - m); a.w = expf(a.w - m);
  b.x = expf(b.x - m); b.y = expf(b.y - m); b.z = expf(b.z - m); b.w = expf(b.w - m);
  float s = a.x + a.y + a.z + a.w + b.x + b.y + b.z + b.w;
#pragma unroll
  for (int off = 32; off; off >>= 1) s += __shfl_xor(s, off);
  float inv = 1.f / s;
  a.x *= inv; a.y *= inv; a.z *= inv; a.w *= inv;
  b.x *= inv; b.y *= inv; b.z *= inv; b.w *= inv;
  *(float4*)&p[lane * 4] = a;
  *(float4*)&p[256 + lane * 4] = b;
}

// ---------------- final tiny GEMM: logits = h1 @ tr_w2^T + b  (N=8) --------
__global__ __launch_bounds__(256) void tr2_k(
    const float* __restrict__ h1, const float* __restrict__ w,
    const float* __restrict__ bias, float* __restrict__ logits)
{
  int wid = threadIdx.x >> 6, lane = threadIdx.x & 63;
  int t = blockIdx.x * 4 + wid;
  const float* x = h1 + (size_t)t * Hh;
  float acc[8];
#pragma unroll
  for (int e = 0; e < 8; ++e) acc[e] = 0.f;
  for (int k = lane; k < Hh; k += 64) {
    float xv = x[k];
#pragma unroll
    for (int e = 0; e < 8; ++e) acc[e] += xv * w[e * Hh + k];
  }
#pragma unroll
  for (int e = 0; e < 8; ++e) {
#pragma unroll
    for (int off = 32; off; off >>= 1) acc[e] += __shfl_xor(acc[e], off);
  }
  if (lane == 0) {
#pragma unroll
    for (int e = 0; e < 8; ++e) logits[(size_t)t * 8 + e] = acc[e] + bias[e];
  }
}

// ---------------- zero fill of dispatch+combine ----------------
__global__ __launch_bounds__(256) void fill0_k(float4* __restrict__ p, long long n4)
{
  long long i = (long long)blockIdx.x * 256 + threadIdx.x;
  long long stride = (long long)gridDim.x * 256;
  float4 z = make_float4(0.f, 0.f, 0.f, 0.f);
  for (; i < n4; i += stride) p[i] = z;
}

// ---------------- router: softmax, top2, slot writes, partial p-sums -------
__global__ __launch_bounds__(256) void router_k(
    float* __restrict__ out, float* __restrict__ partials)
{
  int t = blockIdx.x * 256 + threadIdx.x;            // token 0..4095
  float* lg = out + 100663296 + (size_t)t * 8;       // logits (in-place -> probs)
  float p[8];
#pragma unroll
  for (int e = 0; e < 8; ++e) p[e] = lg[e];
  float m = p[0];
#pragma unroll
  for (int e = 1; e < 8; ++e) m = fmaxf(m, p[e]);
  float s = 0.f;
#pragma unroll
  for (int e = 0; e < 8; ++e) { p[e] = expf(p[e] - m); s += p[e]; }
  float inv = 1.f / s;
#pragma unroll
  for (int e = 0; e < 8; ++e) p[e] *= inv;
#pragma unroll
  for (int e = 0; e < 8; ++e) lg[e] = p[e];          // router_probs out

  int i0 = 0; float v0 = p[0];
#pragma unroll
  for (int e = 1; e < 8; ++e) if (p[e] > v0) { v0 = p[e]; i0 = e; }
  int i1 = -1; float v1 = -1.f;
#pragma unroll
  for (int e = 0; e < 8; ++e) if (e != i0 && p[e] > v1) { v1 = p[e]; i1 = e; }
  float wn = 1.f / (v0 + v1);
  size_t db = (size_t)t * (Ee * CAPc);
  out[db + (size_t)i0 * CAPc] = 1.f;
  out[db + (size_t)i1 * CAPc] = 1.f;
  out[50331648 + db + (size_t)i0 * CAPc] = v0 * wn;
  out[50331648 + db + (size_t)i1 * CAPc] = v1 * wn;

  __shared__ float red[256];
#pragma unroll
  for (int e = 0; e < 8; ++e) {
    red[threadIdx.x] = p[e];
    __syncthreads();
    for (int st = 128; st; st >>= 1) {
      if (threadIdx.x < st) red[threadIdx.x] += red[threadIdx.x + st];
      __syncthreads();
    }
    if (threadIdx.x == 0) partials[blockIdx.x * 8 + e] = red[0];
    __syncthreads();
  }
}

// ---------------- aux loss + cleanup of partials scratch ----------------
__global__ __launch_bounds__(64) void aux_k(float* __restrict__ partials,
                                            float* __restrict__ out)
{
  int lane = threadIdx.x;
  float v = 0.f;
  if (lane < 8) {
    float s = 0.f;
    for (int b = 0; b < 16; ++b) s += partials[b * 8 + lane];
    float pm = s / 4096.f;
    v = pm * logf(pm * 8.f + 1e-9f);
  }
#pragma unroll
  for (int off = 4; off; off >>= 1) v += __shfl_xor(v, off);
  if (lane == 0) out[100696064] = v;
  // zero the partials scratch (it lives inside the combine region)
  partials[lane] = 0.f;
  partials[64 + lane] = 0.f;
}

extern "C" void kernel_launch(void* const* d_in, const int* in_sizes, int n_in,
                              void* d_out, int out_size, void* d_ws, size_t ws_size,
                              hipStream_t stream)
{
  const float* hidden = (const float*)d_in[0];
  const float* pos_emb = (const float*)d_in[1];
  const float* se_w1 = (const float*)d_in[2];
  const float* se_b1 = (const float*)d_in[3];
  const float* se_w2 = (const float*)d_in[4];
  const float* se_b2 = (const float*)d_in[5];
  const float* sexp_w = (const float*)d_in[6];
  const float* sexp_b = (const float*)d_in[7];
  const float* te_w1 = (const float*)d_in[8];
  const float* te_b1 = (const float*)d_in[9];
  const float* te_w2 = (const float*)d_in[10];
  const float* te_b2 = (const float*)d_in[11];
  const float* ain_w = (const float*)d_in[12];
  const float* ain_b = (const float*)d_in[13];
  const float* aout_w = (const float*)d_in[14];
  const float* aout_b = (const float*)d_in[15];
  const float* tr_w1 = (const float*)d_in[16];
  const float* tr_b1 = (const float*)d_in[17];
  const float* tr_w2 = (const float*)d_in[18];
  const float* tr_b2 = (const float*)d_in[19];
  float* out = (float*)d_out;

  // scratch arena inside d_out (dispatch+combine region, zero-filled later)
  float* enc1 = out;                  // [4096,1024]
  float* enc2 = out + 4194304;        // [4096,1024]
  float* qkv  = out + 8388608;        // [4096,3072]
  float* scor = out + 20971520;       // [64,512,512]
  float* attno= out + 37748736;       // [4096,1024]
  float* encf = out + 41943040;       // [4096,1024]
  float* h1   = out + 46137344;       // [4096,1024]
  float* bias1= out + 50331648;       // [512,1024]
  float* psea = out + 50855936;       // [512,1024]
  float* parts= out + 51380224;       // [16,8] (no slot-0 collision: verified)
  float* lgts = out + 100663296;      // logits -> probs region (not zero-filled)

  precompute_k<<<512, 256, 0, stream>>>(pos_emb, se_w1, se_b1, se_w2, se_b2,
                                        sexp_w, sexp_b, te_w1, te_b1, psea, bias1);

  // enc1 = relu(hidden @ te_w1[:, :1024]^T + bias1[s])   (bias1 folds ts/se cols + te_b1)
  gemm_k<false, true, false, true><<<dim3(8, 32, 1), 256, 0, stream>>>(
      hidden, 1024, 0, 0, te_w1, 1026, 0, 0, enc1, 1024, 0, 0,
      1024, 1, nullptr, bias1, 1024, 512, 1.f);

  // enc2 = enc1 @ te_w2^T + te_b2 + psea[s]
  gemm_k<false, false, true, true><<<dim3(8, 32, 1), 256, 0, stream>>>(
      enc1, 1024, 0, 0, te_w2, 1024, 0, 0, enc2, 1024, 0, 0,
      1024, 1, te_b2, psea, 1024, 512, 1.f);

  // qkv = enc2 @ attn_in_w^T + attn_in_b
  gemm_k<false, false, true, false><<<dim3(24, 32, 1), 256, 0, stream>>>(
      enc2, 1024, 0, 0, ain_w, 1024, 0, 0, qkv, 3072, 0, 0,
      1024, 1, ain_b, nullptr, 1, 1, 1.f);

  // scores[b,h] = Q K^T / sqrt(128)
  gemm_k<false, false, false, false><<<dim3(4, 4, 64), 256, 0, stream>>>(
      qkv, 3072, 1572864, 128, qkv + 1024, 3072, 1572864, 128,
      scor, 512, 2097152, 262144,
      128, 8, nullptr, nullptr, 1, 1, 0.08838834764831845f);

  softmax_k<<<8192, 256, 0, stream>>>(scor);

  // attno[b,h] = P @ V
  gemm_k<true, false, false, false><<<dim3(1, 4, 64), 256, 0, stream>>>(
      scor, 512, 2097152, 262144, qkv + 2048, 3072, 1572864, 128,
      attno, 1024, 524288, 128,
      512, 8, nullptr, nullptr, 1, 1, 1.f);

  // encf = attno @ attn_out_w^T + attn_out_b
  gemm_k<false, false, true, false><<<dim3(8, 32, 1), 256, 0, stream>>>(
      attno, 1024, 0, 0, aout_w, 1024, 0, 0, encf, 1024, 0, 0,
      1024, 1, aout_b, nullptr, 1, 1, 1.f);

  // h1 = relu(encf @ tr_w1^T + tr_b1)
  gemm_k<false, true, true, false><<<dim3(8, 32, 1), 256, 0, stream>>>(
      encf, 1024, 0, 0, tr_w1, 1024, 0, 0, h1, 1024, 0, 0,
      1024, 1, tr_b1, nullptr, 1, 1, 1.f);

  // logits (into probs region, survives the fill)
  tr2_k<<<1024, 256, 0, stream>>>(h1, tr_w2, tr_b2, lgts);

  // zero dispatch+combine (also wipes all arena scratch)
  fill0_k<<<2048, 256, 0, stream>>>((float4*)out, 25165824LL);

  // softmax/top2/slots/probs + partial p-mean sums
  router_k<<<16, 256, 0, stream>>>(out, parts);

  // aux loss + zero the partials scratch
  aux_k<<<1, 64, 0, stream>>>(parts, out);
}

// Round 2
// 1225.832 us; speedup vs baseline: 1.0669x; 1.0669x over previous
//
#include <hip/hip_runtime.h>
#include <hip/hip_bf16.h>

// TimeMoERouter: B=8 S=512 H=1024 E=8 TOPK=2 NHEADS=8 DH=128 CAP=1536
// Round 2: all GEMMs on bf16 MFMA with split-precision (hi+lo bf16, 3 segments:
// hi*hi + hi*lo + lo*hi) => fp32-grade accuracy at MFMA rates.
// d_out (402MB dispatch+combine region) is the scratch arena; fill0 re-zeroes it.

#define Hh 1024

typedef __attribute__((ext_vector_type(8))) short short8v;
typedef __attribute__((ext_vector_type(4))) float f32x4;

static __device__ __forceinline__ ushort f2bf(float x) {
  uint u = __float_as_uint(x);
  u += 0x7FFF + ((u >> 16) & 1);          // round-to-nearest-even
  return (ushort)(u >> 16);
}
static __device__ __forceinline__ float bf2f(ushort h) {
  return __uint_as_float(((uint)h) << 16);
}

// ---------------- split-precision MFMA GEMM ----------------
// C[m,n] = alpha * sum_k A[m,k]*B[n,k]  over 3 segments: (aHi,bHi),(aHi,bLo),(aLo,bHi)
// A: ushort bf16 buffer, row stride lda, hi at col aHi+k, lo at col aLo+k.
// B: TRANSB_STAGE=false: [N][*] rows with hi/lo col offsets (weight-style).
//    TRANSB_STAGE=true : [K][*] rows (k-major, e.g. V), cols bo+n0+n.
// EPI: 0 = fp32 C;  1 = split bf16 (hi at col n, lo at col n+splitOff).
// Batch via blockIdx.z: zj=z/zdiv, zi=z%zdiv; element offsets sXmaj/sXmin.
// Tile 128x128, BK=64, 4 waves (2x2), 16x16x32 bf16 MFMA, XOR-swizzled LDS.
template<bool TRANSB_STAGE, int EPI, bool RELU, bool HAS_BN, bool HAS_BSN>
__global__ __launch_bounds__(256) void mgemm_k(
    const ushort* __restrict__ A, int lda, long long sAmaj, long long sAmin, int aHi, int aLo,
    const ushort* __restrict__ B, int ldb, long long sBmaj, long long sBmin, int bHi, int bLo,
    float* __restrict__ Cf, ushort* __restrict__ Ch, int ldc, long long sCmaj, long long sCmin,
    int splitOff, int Kd, int zdiv,
    const float* __restrict__ bN, const float* __restrict__ bSN, int ldbs, int smod,
    float alpha)
{
  int z = blockIdx.z;
  int zj = z / zdiv, zi = z - zj * zdiv;
  A += (size_t)zj * sAmaj + (size_t)zi * sAmin;
  B += (size_t)zj * sBmaj + (size_t)zi * sBmin;
  long long coff = (long long)zj * sCmaj + (long long)zi * sCmin;

  int m0 = blockIdx.y * 128, n0 = blockIdx.x * 128;
  __shared__ __align__(16) ushort As[128 * 64];
  __shared__ __align__(16) ushort Bs[128 * 64];

  int t = threadIdx.x;
  int l = t & 63, w = t >> 6;
  int wm = w >> 1, wn = w & 1;

  f32x4 acc[4][4];
#pragma unroll
  for (int i = 0; i < 4; ++i)
#pragma unroll
    for (int j = 0; j < 4; ++j) acc[i][j] = (f32x4){0.f, 0.f, 0.f, 0.f};

  int srow = t >> 1, scc = (t & 1) * 4;    // A staging: row, first 16B-chunk
  int tbk = t >> 2, tbn = (t & 3) * 4;     // TRANSB staging: k-row, first n-chunk

  for (int seg = 0; seg < 3; ++seg) {
    int ao = (seg == 2) ? aLo : aHi;
    int bo = (seg == 1) ? bLo : bHi;
    for (int k0 = 0; k0 < Kd; k0 += 64) {
      int4 av[4], bv[4];
      {
        const int4* agp = (const int4*)(A + (size_t)(m0 + srow) * lda + ao + k0 + scc * 8);
#pragma unroll
        for (int i = 0; i < 4; ++i) av[i] = agp[i];
      }
      if (!TRANSB_STAGE) {
        const int4* bgp = (const int4*)(B + (size_t)(n0 + srow) * ldb + bo + k0 + scc * 8);
#pragma unroll
        for (int i = 0; i < 4; ++i) bv[i] = bgp[i];
      } else {
        const int4* bgp = (const int4*)(B + (size_t)(k0 + tbk) * ldb + bo + n0 + tbn * 8);
#pragma unroll
        for (int i = 0; i < 4; ++i) bv[i] = bgp[i];
      }
      __syncthreads();   // prior MFMA reads done before overwrite
#pragma unroll
      for (int i = 0; i < 4; ++i)
        *(int4*)((char*)As + ((srow * 128 + (scc + i) * 16) ^ ((srow & 7) << 4))) = av[i];
      if (!TRANSB_STAGE) {
#pragma unroll
        for (int i = 0; i < 4; ++i)
          *(int4*)((char*)Bs + ((srow * 128 + (scc + i) * 16) ^ ((srow & 7) << 4))) = bv[i];
      } else {
#pragma unroll
        for (int i = 0; i < 4; ++i) {
          ushort tmp[8];
          *(int4*)tmp = bv[i];
          int nb = (tbn + i) * 8;
#pragma unroll
          for (int jj = 0; jj < 8; ++jj) {
            int nn = nb + jj;
            *(ushort*)((char*)Bs + ((nn * 128 + tbk * 2) ^ ((nn & 7) << 4))) = tmp[jj];
          }
        }
      }
      __syncthreads();
#pragma unroll
      for (int kk = 0; kk < 2; ++kk) {
        short8v af[4], bf[4];
#pragma unroll
        for (int mi = 0; mi < 4; ++mi) {
          int row = wm * 64 + mi * 16 + (l & 15);
          af[mi] = *(const short8v*)((char*)As +
                    ((row * 128 + kk * 64 + (l >> 4) * 16) ^ ((row & 7) << 4)));
        }
#pragma unroll
        for (int ni = 0; ni < 4; ++ni) {
          int row = wn * 64 + ni * 16 + (l & 15);
          bf[ni] = *(const short8v*)((char*)Bs +
                    ((row * 128 + kk * 64 + (l >> 4) * 16) ^ ((row & 7) << 4)));
        }
#pragma unroll
        for (int mi = 0; mi < 4; ++mi)
#pragma unroll
          for (int ni = 0; ni < 4; ++ni)
            acc[mi][ni] = __builtin_amdgcn_mfma_f32_16x16x32_bf16(af[mi], bf[ni], acc[mi][ni], 0, 0, 0);
      }
    }
  }

  // epilogue: C[m][n], m = m0+wm*64+mi*16+(l>>4)*4+j, n = n0+wn*64+ni*16+(l&15)
#pragma unroll
  for (int mi = 0; mi < 4; ++mi) {
#pragma unroll
    for (int j = 0; j < 4; ++j) {
      int m = m0 + wm * 64 + mi * 16 + (l >> 4) * 4 + j;
#pragma unroll
      for (int ni = 0; ni < 4; ++ni) {
        int n = n0 + wn * 64 + ni * 16 + (l & 15);
        float x = acc[mi][ni][j] * alpha;
        if (HAS_BN) x += bN[n];
        if (HAS_BSN) x += bSN[(size_t)(m % smod) * ldbs + n];
        if (RELU) x = fmaxf(x, 0.f);
        if (EPI == 0) {
          Cf[coff + (size_t)m * ldc + n] = x;
        } else {
          ushort h = f2bf(x);
          ushort lo2 = f2bf(x - bf2f(h));
          Ch[coff + (size_t)m * ldc + n] = h;
          Ch[coff + (size_t)m * ldc + n + splitOff] = lo2;
        }
      }
    }
  }
}

// ---------------- fp32 [N][K] -> bf16 hi|lo [N][2K] ----------------
__global__ __launch_bounds__(256) void convert_k(
    const float* __restrict__ W, int lda, ushort* __restrict__ Whl, int K)
{
  int r = blockIdx.x;
  int c = threadIdx.x * 4;
  const float* src = W + (size_t)r * lda + c;
  float x0 = src[0], x1 = src[1], x2 = src[2], x3 = src[3];
  ushort4 h, lo;
  h.x = f2bf(x0); lo.x = f2bf(x0 - bf2f(h.x));
  h.y = f2bf(x1); lo.y = f2bf(x1 - bf2f(h.y));
  h.z = f2bf(x2); lo.z = f2bf(x2 - bf2f(h.z));
  h.w = f2bf(x3); lo.w = f2bf(x3 - bf2f(h.w));
  ushort* dst = Whl + (size_t)r * 2 * K;
  *(ushort4*)&dst[c] = h;
  *(ushort4*)&dst[K + c] = lo;
}

// ---------------- seasonal / positional precompute (fp32) ----------------
__global__ __launch_bounds__(256) void precompute_k(
    const float* __restrict__ pos_emb,
    const float* __restrict__ se_w1, const float* __restrict__ se_b1,
    const float* __restrict__ se_w2, const float* __restrict__ se_b2,
    const float* __restrict__ sexp_w, const float* __restrict__ sexp_b,
    const float* __restrict__ te_w1, const float* __restrict__ te_b1,
    float* __restrict__ psea, float* __restrict__ bias1)
{
  int s = blockIdx.x, t = threadIdx.x;
  float ts = (float)s;
  float se = sinf(((ts * 2.0f) * 3.14159274101257324f) / 24.0f);
  __shared__ float l1[256], l2[256];
  l1[t] = fmaxf(se * se_w1[t] + se_b1[t], 0.f);
  __syncthreads();
  {
    float a = se_b2[t];
    const float* wr = se_w2 + (size_t)t * 256;
    for (int i = 0; i < 256; ++i) a += l1[i] * wr[i];
    l2[t] = a;
  }
  __syncthreads();
#pragma unroll
  for (int r = 0; r < 4; ++r) {
    int h = r * 256 + t;
    float v = sexp_b[h];
    const float* wr = sexp_w + (size_t)h * 256;
    for (int j = 0; j < 256; ++j) v += l2[j] * wr[j];
    psea[s * Hh + h] = pos_emb[s * Hh + h] + v;
    bias1[s * Hh + h] = te_b1[h] + ts * te_w1[(size_t)h * 1026 + 1024]
                                 + se * te_w1[(size_t)h * 1026 + 1025];
  }
}

// ---------------- softmax over score rows; writes split P in place --------
__global__ __launch_bounds__(256) void softmax2_k(float* __restrict__ S)
{
  int row = blockIdx.x * 4 + (threadIdx.x >> 6);
  int lane = threadIdx.x & 63;
  float* p = S + (size_t)row * 512;
  float4 a = *(float4*)&p[lane * 4];
  float4 b = *(float4*)&p[256 + lane * 4];
  float m = fmaxf(fmaxf(fmaxf(a.x, a.y), fmaxf(a.z, a.w)),
                  fmaxf(fmaxf(b.x, b.y), fmaxf(b.z, b.w)));
#pragma unroll
  for (int off = 32; off; off >>= 1) m = fmaxf(m, __shfl_xor(m, off));
  a.x = expf(a.x - m); a.y = expf(a.y - m); a.z = expf(a.z - m); a.w = expf(a.w - m);
  b.x = expf(b.x - m); b.y = expf(b.y - m); b.z = expf(b.z - m); b.w = expf(b.w - m);
  float s = a.x + a.y + a.z + a.w + b.x + b.y + b.z + b.w;
#pragma unroll
  for (int off = 32; off; off >>= 1) s += __shfl_xor(s, off);
  float inv = 1.f / s;
  a.x *= inv; a.y *= inv; a.z *= inv; a.w *= inv;
  b.x *= inv; b.y *= inv; b.z *= inv; b.w *= inv;
  // split write in place: row becomes [hi 512 | lo 512] ushorts
  ushort* u = (ushort*)S + (size_t)row * 1024;
  ushort4 ha, la, hb, lb;
  ha.x = f2bf(a.x); la.x = f2bf(a.x - bf2f(ha.x));
  ha.y = f2bf(a.y); la.y = f2bf(a.y - bf2f(ha.y));
  ha.z = f2bf(a.z); la.z = f2bf(a.z - bf2f(ha.z));
  ha.w = f2bf(a.w); la.w = f2bf(a.w - bf2f(ha.w));
  hb.x = f2bf(b.x); lb.x = f2bf(b.x - bf2f(hb.x));
  hb.y = f2bf(b.y); lb.y = f2bf(b.y - bf2f(hb.y));
  hb.z = f2bf(b.z); lb.z = f2bf(b.z - bf2f(hb.z));
  hb.w = f2bf(b.w); lb.w = f2bf(b.w - bf2f(hb.w));
  *(ushort4*)&u[lane * 4] = ha;
  *(ushort4*)&u[512 + lane * 4] = la;
  *(ushort4*)&u[256 + lane * 4] = hb;
  *(ushort4*)&u[768 + lane * 4] = lb;
}

// ---------------- logits = h1 @ tr_w2^T + b  (N=8, fp32 VALU) ----------
__global__ __launch_bounds__(256) void tr2_k(
    const float* __restrict__ h1, const float* __restrict__ w,
    const float* __restrict__ bias, float* __restrict__ logits)
{
  int wid = threadIdx.x >> 6, lane = threadIdx.x & 63;
  int t = blockIdx.x * 4 + wid;
  const float* x = h1 + (size_t)t * Hh;
  float acc[8];
#pragma unroll
  for (int e = 0; e < 8; ++e) acc[e] = 0.f;
  for (int k = lane; k < Hh; k += 64) {
    float xv = x[k];
#pragma unroll
    for (int e = 0; e < 8; ++e) acc[e] += xv * w[e * Hh + k];
  }
#pragma unroll
  for (int e = 0; e < 8; ++e) {
#pragma unroll
    for (int off = 32; off; off >>= 1) acc[e] += __shfl_xor(acc[e], off);
  }
  if (lane == 0) {
#pragma unroll
    for (int e = 0; e < 8; ++e) logits[(size_t)t * 8 + e] = acc[e] + bias[e];
  }
}

// ---------------- zero fill of dispatch+combine ----------------
__global__ __launch_bounds__(256) void fill0_k(float4* __restrict__ p, long long n4)
{
  long long i = (long long)blockIdx.x * 256 + threadIdx.x;
  long long stride = (long long)gridDim.x * 256;
  float4 z = make_float4(0.f, 0.f, 0.f, 0.f);
  for (; i < n4; i += stride) p[i] = z;
}

// ---------------- router: softmax, top2, slot writes, partial p-sums -------
__global__ __launch_bounds__(256) void router_k(
    float* __restrict__ out, float* __restrict__ partials)
{
  int t = blockIdx.x * 256 + threadIdx.x;            // token 0..4095
  float* lg = out + 100663296 + (size_t)t * 8;       // logits (in-place -> probs)
  float p[8];
#pragma unroll
  for (int e = 0; e < 8; ++e) p[e] = lg[e];
  float m = p[0];
#pragma unroll
  for (int e = 1; e < 8; ++e) m = fmaxf(m, p[e]);
  float s = 0.f;
#pragma unroll
  for (int e = 0; e < 8; ++e) { p[e] = expf(p[e] - m); s += p[e]; }
  float inv = 1.f / s;
#pragma unroll
  for (int e = 0; e < 8; ++e) p[e] *= inv;
#pragma unroll
  for (int e = 0; e < 8; ++e) lg[e] = p[e];          // router_probs out

  int i0 = 0; float v0 = p[0];
#pragma unroll
  for (int e = 1; e < 8; ++e) if (p[e] > v0) { v0 = p[e]; i0 = e; }
  int i1 = -1; float v1 = -1.f;
#pragma unroll
  for (int e = 0; e < 8; ++e) if (e != i0 && p[e] > v1) { v1 = p[e]; i1 = e; }
  float wn = 1.f / (v0 + v1);
  size_t db = (size_t)t * (8 * 1536);
  out[db + (size_t)i0 * 1536] = 1.f;
  out[db + (size_t)i1 * 1536] = 1.f;
  out[50331648 + db + (size_t)i0 * 1536] = v0 * wn;
  out[50331648 + db + (size_t)i1 * 1536] = v1 * wn;

  __shared__ float red[256];
#pragma unroll
  for (int e = 0; e < 8; ++e) {
    red[threadIdx.x] = p[e];
    __syncthreads();
    for (int st = 128; st; st >>= 1) {
      if (threadIdx.x < st) red[threadIdx.x] += red[threadIdx.x + st];
      __syncthreads();
    }
    if (threadIdx.x == 0) partials[blockIdx.x * 8 + e] = red[0];
    __syncthreads();
  }
}

// ---------------- aux loss + cleanup of partials scratch ----------------
__global__ __launch_bounds__(64) void aux_k(float* __restrict__ partials,
                                            float* __restrict__ out)
{
  int lane = threadIdx.x;
  float v = 0.f;
  if (lane < 8) {
    float s = 0.f;
    for (int b = 0; b < 16; ++b) s += partials[b * 8 + lane];
    float pm = s / 4096.f;
    v = pm * logf(pm * 8.f + 1e-9f);
  }
#pragma unroll
  for (int off = 4; off; off >>= 1) v += __shfl_xor(v, off);
  if (lane == 0) out[100696064] = v;
  partials[lane] = 0.f;
  partials[64 + lane] = 0.f;
}

extern "C" void kernel_launch(void* const* d_in, const int* in_sizes, int n_in,
                              void* d_out, int out_size, void* d_ws, size_t ws_size,
                              hipStream_t stream)
{
  const float* hidden = (const float*)d_in[0];
  const float* pos_emb = (const float*)d_in[1];
  const float* se_w1 = (const float*)d_in[2];
  const float* se_b1 = (const float*)d_in[3];
  const float* se_w2 = (const float*)d_in[4];
  const float* se_b2 = (const float*)d_in[5];
  const float* sexp_w = (const float*)d_in[6];
  const float* sexp_b = (const float*)d_in[7];
  const float* te_w1 = (const float*)d_in[8];
  const float* te_b1 = (const float*)d_in[9];
  const float* te_w2 = (const float*)d_in[10];
  const float* te_b2 = (const float*)d_in[11];
  const float* ain_w = (const float*)d_in[12];
  const float* ain_b = (const float*)d_in[13];
  const float* aout_w = (const float*)d_in[14];
  const float* aout_b = (const float*)d_in[15];
  const float* tr_w1 = (const float*)d_in[16];
  const float* tr_b1 = (const float*)d_in[17];
  const float* tr_w2 = (const float*)d_in[18];
  const float* tr_b2 = (const float*)d_in[19];
  float* out = (float*)d_out;

  // scratch arena: byte offsets inside d_out's dispatch+combine region (402MB)
  char* arena = (char*)d_out;
  ushort* W1    = (ushort*)(arena + 0);          // te_w1 hi|lo  [1024][2048]
  ushort* W2h   = (ushort*)(arena + 4194304);    // te_w2
  ushort* Wa    = (ushort*)(arena + 8388608);    // attn_in [3072][2048]
  ushort* Wo    = (ushort*)(arena + 20971520);   // attn_out
  ushort* Wt    = (ushort*)(arena + 25165824);   // tr_w1
  ushort* hid2  = (ushort*)(arena + 29360128);   // hidden   [4096][2048]
  ushort* enc1  = (ushort*)(arena + 46137344);   // [4096][2048]
  ushort* enc2  = (ushort*)(arena + 62914560);   // [4096][2048]
  ushort* qkv2  = (ushort*)(arena + 79691776);   // [4096][6144] hi|lo of qkv
  float*  scor  = (float*)(arena + 130023424);   // [64][512][512] -> P2 split in place
  ushort* attno = (ushort*)(arena + 197132288);  // [4096][2048]
  ushort* encf  = (ushort*)(arena + 213909504);  // [4096][2048]
  float*  h1    = (float*)(arena + 230686720);   // [4096][1024] fp32
  float*  psea  = (float*)(arena + 247463936);   // [512][1024]
  float*  bias1 = (float*)(arena + 249561088);   // [512][1024]
  float*  parts = out + 51380224;                // [16][8], zeroed by aux_k
  float*  lgts  = out + 100663296;               // logits -> probs region

  // weight / input hi-lo expansions
  convert_k<<<1024, 256, 0, stream>>>(te_w1, 1026, W1, 1024);
  convert_k<<<1024, 256, 0, stream>>>(te_w2, 1024, W2h, 1024);
  convert_k<<<3072, 256, 0, stream>>>(ain_w, 1024, Wa, 1024);
  convert_k<<<1024, 256, 0, stream>>>(aout_w, 1024, Wo, 1024);
  convert_k<<<1024, 256, 0, stream>>>(tr_w1, 1024, Wt, 1024);
  convert_k<<<4096, 256, 0, stream>>>(hidden, 1024, hid2, 1024);

  precompute_k<<<512, 256, 0, stream>>>(pos_emb, se_w1, se_b1, se_w2, se_b2,
                                        sexp_w, sexp_b, te_w1, te_b1, psea, bias1);

  // G1: enc1 = relu(hidden @ te_w1'^T + bias1[s])  (split out)
  mgemm_k<false, 1, true, false, true><<<dim3(8, 32, 1), 256, 0, stream>>>(
      hid2, 2048, 0, 0, 0, 1024,
      W1, 2048, 0, 0, 0, 1024,
      nullptr, enc1, 2048, 0, 0, 1024,
      1024, 1, nullptr, bias1, 1024, 512, 1.f);

  // G2: enc2 = enc1 @ te_w2^T + te_b2 + psea[s]  (split out)
  mgemm_k<false, 1, false, true, true><<<dim3(8, 32, 1), 256, 0, stream>>>(
      enc1, 2048, 0, 0, 0, 1024,
      W2h, 2048, 0, 0, 0, 1024,
      nullptr, enc2, 2048, 0, 0, 1024,
      1024, 1, te_b2, psea, 1024, 512, 1.f);

  // G3: qkv = enc2 @ attn_in_w^T + attn_in_b  (split out, [4096][3072|3072])
  mgemm_k<false, 1, false, true, false><<<dim3(24, 32, 1), 256, 0, stream>>>(
      enc2, 2048, 0, 0, 0, 1024,
      Wa, 2048, 0, 0, 0, 1024,
      nullptr, qkv2, 6144, 0, 0, 3072,
      1024, 1, ain_b, nullptr, 1, 1, 1.f);

  // G4: scores[b,h] = Q K^T / sqrt(128)  (fp32 out)
  mgemm_k<false, 0, false, false, false><<<dim3(4, 4, 64), 256, 0, stream>>>(
      qkv2, 6144, 3145728, 128, 0, 3072,
      qkv2, 6144, 3145728, 128, 1024, 4096,
      scor, nullptr, 512, 2097152, 262144,
      0, 128, 8, nullptr, nullptr, 1, 1, 0.08838834764831845f);

  softmax2_k<<<8192, 256, 0, stream>>>(scor);

  // G5: attno[b,h] = P @ V  (A = split P in scor, B = V rows k-major, split out)
  mgemm_k<true, 1, false, false, false><<<dim3(1, 4, 64), 256, 0, stream>>>(
      (const ushort*)scor, 1024, 4194304, 524288, 0, 512,
      qkv2, 6144, 3145728, 128, 2048, 5120,
      nullptr, attno, 2048, 1048576, 128,
      1024, 512, 8, nullptr, nullptr, 1, 1, 1.f);

  // G6: encf = attno @ attn_out_w^T + attn_out_b  (split out)
  mgemm_k<false, 1, false, true, false><<<dim3(8, 32, 1), 256, 0, stream>>>(
      attno, 2048, 0, 0, 0, 1024,
      Wo, 2048, 0, 0, 0, 1024,
      nullptr, encf, 2048, 0, 0, 1024,
      1024, 1, aout_b, nullptr, 1, 1, 1.f);

  // G7: h1 = relu(encf @ tr_w1^T + tr_b1)  (fp32 out)
  mgemm_k<false, 0, true, true, false><<<dim3(8, 32, 1), 256, 0, stream>>>(
      encf, 2048, 0, 0, 0, 1024,
      Wt, 2048, 0, 0, 0, 1024,
      h1, nullptr, 1024, 0, 0, 0,
      1024, 1, tr_b1, nullptr, 1, 1, 1.f);

  tr2_k<<<1024, 256, 0, stream>>>(h1, tr_w2, tr_b2, lgts);

  // zero dispatch+combine (wipes all arena scratch)
  fill0_k<<<4096, 256, 0, stream>>>((float4*)out, 25165824LL);

  router_k<<<16, 256, 0, stream>>>(out, parts);
  aux_k<<<1, 64, 0, stream>>>(parts, out);
}

// Round 3
// 1045.504 us; speedup vs baseline: 1.2509x; 1.1725x over previous
//
#include <hip/hip_runtime.h>
#include <hip/hip_bf16.h>

// TimeMoERouter: B=8 S=512 H=1024 E=8 TOPK=2 NHEADS=8 DH=128 CAP=1536
// Round 3: split-precision MFMA GEMM with
//  - merged-segment staging (Ah,Al,Bh,Bl tiles per k-step, 3 MFMA passes)
//  - LDS-bounce coalesced split-bf16 epilogue (kills 12x write amplification)
//  - XCD-aware bijective block swizzle
// d_out (402MB dispatch+combine region) is the scratch arena; fill0 re-zeroes it.

#define Hh 1024

typedef __attribute__((ext_vector_type(8))) short short8v;
typedef __attribute__((ext_vector_type(4))) float f32x4;

static __device__ __forceinline__ ushort f2bf(float x) {
  uint u = __float_as_uint(x);
  u += 0x7FFF + ((u >> 16) & 1);          // round-to-nearest-even
  return (ushort)(u >> 16);
}
static __device__ __forceinline__ float bf2f(ushort h) {
  return __uint_as_float(((uint)h) << 16);
}

// ---------------- split-precision MFMA GEMM ----------------
// C[m,n] = alpha * sum_k A[m,k]*B[n,k] over segments (aHi,bHi)+(aHi,bLo)+(aLo,bHi).
// A: bf16 buffer, row stride lda, hi at col aHi+k, lo at col aLo+k.
// B: TRANSB_STAGE=false: [N][*] weight-style rows; true: [K][*] k-major rows.
// EPI: 0 = fp32 C; 1 = split bf16 (hi at col n, lo at col n+splitOff).
// Tile 128x128, BK=64, 4 waves (2x2), 16x16x32 bf16 MFMA, XOR-swizzled LDS.
template<bool TRANSB_STAGE, int EPI, bool RELU, bool HAS_BN, bool HAS_BSN>
__global__ __launch_bounds__(256) void mgemm_k(
    const ushort* __restrict__ A, int lda, long long sAmaj, long long sAmin, int aHi, int aLo,
    const ushort* __restrict__ B, int ldb, long long sBmaj, long long sBmin, int bHi, int bLo,
    float* __restrict__ Cf, ushort* __restrict__ Ch, int ldc, long long sCmaj, long long sCmin,
    int splitOff, int Kd, int zdiv,
    const float* __restrict__ bN, const float* __restrict__ bSN, int ldbs, int smod,
    float alpha)
{
  // XCD-aware bijective swizzle (all grids are multiples of 8)
  int gx = gridDim.x, gy = gridDim.y;
  int lin = (blockIdx.z * gy + blockIdx.y) * gx + blockIdx.x;
  int nwg = gx * gy * gridDim.z;
  int cpx = nwg >> 3;
  int swz = (lin & 7) * cpx + (lin >> 3);
  int bz = swz / (gx * gy);
  int rem = swz - bz * (gx * gy);
  int by = rem / gx, bx = rem - by * gx;

  int zj = bz / zdiv, zi = bz - zj * zdiv;
  A += (size_t)zj * sAmaj + (size_t)zi * sAmin;
  B += (size_t)zj * sBmaj + (size_t)zi * sBmin;
  long long coff = (long long)zj * sCmaj + (long long)zi * sCmin;

  int m0 = by * 128, n0 = bx * 128;

  __shared__ __align__(16) ushort smem[32768];   // 64 KB
  ushort* Ahs = smem;                            // [128][64]
  ushort* Als = smem + 8192;
  ushort* Bhs = smem + 16384;
  ushort* Bls = smem + 24576;

  int t = threadIdx.x;
  int l = t & 63, w = t >> 6;
  int wm = w >> 1, wn = w & 1;

  f32x4 acc[4][4];
#pragma unroll
  for (int i = 0; i < 4; ++i)
#pragma unroll
    for (int j = 0; j < 4; ++j) acc[i][j] = (f32x4){0.f, 0.f, 0.f, 0.f};

  int srow = t >> 1, scc = (t & 1) * 4;    // row-major staging: row, first 16B chunk
  int tbk = t >> 2, tbn = (t & 3) * 4;     // TRANSB staging: k-row, first n-chunk

  for (int k0 = 0; k0 < Kd; k0 += 64) {
    int4 avh[4], avl[4], bvh[4], bvl[4];
    {
      const int4* agh = (const int4*)(A + (size_t)(m0 + srow) * lda + aHi + k0 + scc * 8);
      const int4* agl = (const int4*)(A + (size_t)(m0 + srow) * lda + aLo + k0 + scc * 8);
#pragma unroll
      for (int i = 0; i < 4; ++i) { avh[i] = agh[i]; avl[i] = agl[i]; }
    }
    if (!TRANSB_STAGE) {
      const int4* bgh = (const int4*)(B + (size_t)(n0 + srow) * ldb + bHi + k0 + scc * 8);
      const int4* bgl = (const int4*)(B + (size_t)(n0 + srow) * ldb + bLo + k0 + scc * 8);
#pragma unroll
      for (int i = 0; i < 4; ++i) { bvh[i] = bgh[i]; bvl[i] = bgl[i]; }
    } else {
      const int4* bgh = (const int4*)(B + (size_t)(k0 + tbk) * ldb + bHi + n0 + tbn * 8);
      const int4* bgl = (const int4*)(B + (size_t)(k0 + tbk) * ldb + bLo + n0 + tbn * 8);
#pragma unroll
      for (int i = 0; i < 4; ++i) { bvh[i] = bgh[i]; bvl[i] = bgl[i]; }
    }
    __syncthreads();   // prior MFMA reads done before overwrite
#pragma unroll
    for (int i = 0; i < 4; ++i) {
      int bo2 = (srow * 128 + (scc + i) * 16) ^ ((srow & 7) << 4);
      *(int4*)((char*)Ahs + bo2) = avh[i];
      *(int4*)((char*)Als + bo2) = avl[i];
    }
    if (!TRANSB_STAGE) {
#pragma unroll
      for (int i = 0; i < 4; ++i) {
        int bo2 = (srow * 128 + (scc + i) * 16) ^ ((srow & 7) << 4);
        *(int4*)((char*)Bhs + bo2) = bvh[i];
        *(int4*)((char*)Bls + bo2) = bvl[i];
      }
    } else {
#pragma unroll
      for (int i = 0; i < 4; ++i) {
        ushort tmph[8], tmpl[8];
        *(int4*)tmph = bvh[i];
        *(int4*)tmpl = bvl[i];
        int nb = (tbn + i) * 8;
#pragma unroll
        for (int jj = 0; jj < 8; ++jj) {
          int nn = nb + jj;
          int bo2 = (nn * 128 + tbk * 2) ^ ((nn & 7) << 4);
          *(ushort*)((char*)Bhs + bo2) = tmph[jj];
          *(ushort*)((char*)Bls + bo2) = tmpl[jj];
        }
      }
    }
    __syncthreads();
#pragma unroll
    for (int kk = 0; kk < 2; ++kk) {
      short8v afh[4], afl[4], bfh[4], bfl[4];
#pragma unroll
      for (int mi = 0; mi < 4; ++mi) {
        int row = wm * 64 + mi * 16 + (l & 15);
        int bo2 = (row * 128 + kk * 64 + (l >> 4) * 16) ^ ((row & 7) << 4);
        afh[mi] = *(const short8v*)((char*)Ahs + bo2);
        afl[mi] = *(const short8v*)((char*)Als + bo2);
      }
#pragma unroll
      for (int ni = 0; ni < 4; ++ni) {
        int row = wn * 64 + ni * 16 + (l & 15);
        int bo2 = (row * 128 + kk * 64 + (l >> 4) * 16) ^ ((row & 7) << 4);
        bfh[ni] = *(const short8v*)((char*)Bhs + bo2);
        bfl[ni] = *(const short8v*)((char*)Bls + bo2);
      }
#pragma unroll
      for (int mi = 0; mi < 4; ++mi)
#pragma unroll
        for (int ni = 0; ni < 4; ++ni) {
          acc[mi][ni] = __builtin_amdgcn_mfma_f32_16x16x32_bf16(afh[mi], bfh[ni], acc[mi][ni], 0, 0, 0);
          acc[mi][ni] = __builtin_amdgcn_mfma_f32_16x16x32_bf16(afh[mi], bfl[ni], acc[mi][ni], 0, 0, 0);
          acc[mi][ni] = __builtin_amdgcn_mfma_f32_16x16x32_bf16(afl[mi], bfh[ni], acc[mi][ni], 0, 0, 0);
        }
    }
  }

  // fold alpha + biases + relu into acc
#pragma unroll
  for (int mi = 0; mi < 4; ++mi)
#pragma unroll
    for (int j = 0; j < 4; ++j) {
      int m = m0 + wm * 64 + mi * 16 + (l >> 4) * 4 + j;
#pragma unroll
      for (int ni = 0; ni < 4; ++ni) {
        int n = n0 + wn * 64 + ni * 16 + (l & 15);
        float x = acc[mi][ni][j] * alpha;
        if (HAS_BN) x += bN[n];
        if (HAS_BSN) x += bSN[(size_t)(m % smod) * ldbs + n];
        if (RELU) x = fmaxf(x, 0.f);
        acc[mi][ni][j] = x;
      }
    }

  if (EPI == 0) {
#pragma unroll
    for (int mi = 0; mi < 4; ++mi)
#pragma unroll
      for (int j = 0; j < 4; ++j) {
        int m = m0 + wm * 64 + mi * 16 + (l >> 4) * 4 + j;
#pragma unroll
        for (int ni = 0; ni < 4; ++ni) {
          int n = n0 + wn * 64 + ni * 16 + (l & 15);
          Cf[coff + (size_t)m * ldc + n] = acc[mi][ni][j];
        }
      }
  } else {
    // LDS-bounce split epilogue: hi pass then lo pass, coalesced int4 stores
    __syncthreads();
    ushort* Es = smem;                     // [128][128] ushort = 32KB
#pragma unroll
    for (int pass = 0; pass < 2; ++pass) {
#pragma unroll
      for (int mi = 0; mi < 4; ++mi)
#pragma unroll
        for (int j = 0; j < 4; ++j) {
          int lr = wm * 64 + mi * 16 + (l >> 4) * 4 + j;
#pragma unroll
          for (int ni = 0; ni < 4; ++ni) {
            int lcb = (wn * 64 + ni * 16 + (l & 15)) * 2;
            float x = acc[mi][ni][j];
            ushort h = f2bf(x);
            ushort vv = (pass == 0) ? h : f2bf(x - bf2f(h));
            *(ushort*)((char*)Es + ((lr * 256 + lcb) ^ ((lr & 7) << 4))) = vv;
          }
        }
      __syncthreads();
      int off = (pass == 0) ? 0 : splitOff;
#pragma unroll
      for (int r = 0; r < 8; ++r) {
        int idx = r * 256 + t;
        int row = idx >> 4, cb = (idx & 15) * 16;
        int4 v = *(const int4*)((char*)Es + ((row * 256 + cb) ^ ((row & 7) << 4)));
        *(int4*)((char*)(Ch + coff + (size_t)(m0 + row) * ldc + off + n0) + cb) = v;
      }
      if (pass == 0) __syncthreads();
    }
  }
}

// ---------------- fp32 [N][K] -> bf16 hi|lo [N][2K] ----------------
__global__ __launch_bounds__(256) void convert_k(
    const float* __restrict__ W, int lda, ushort* __restrict__ Whl, int K)
{
  int r = blockIdx.x;
  int c = threadIdx.x * 4;
  const float* src = W + (size_t)r * lda + c;
  float x0 = src[0], x1 = src[1], x2 = src[2], x3 = src[3];
  ushort4 h, lo;
  h.x = f2bf(x0); lo.x = f2bf(x0 - bf2f(h.x));
  h.y = f2bf(x1); lo.y = f2bf(x1 - bf2f(h.y));
  h.z = f2bf(x2); lo.z = f2bf(x2 - bf2f(h.z));
  h.w = f2bf(x3); lo.w = f2bf(x3 - bf2f(h.w));
  ushort* dst = Whl + (size_t)r * 2 * K;
  *(ushort4*)&dst[c] = h;
  *(ushort4*)&dst[K + c] = lo;
}

// ---------------- seasonal / positional precompute (fp32) ----------------
__global__ __launch_bounds__(256) void precompute_k(
    const float* __restrict__ pos_emb,
    const float* __restrict__ se_w1, const float* __restrict__ se_b1,
    const float* __restrict__ se_w2, const float* __restrict__ se_b2,
    const float* __restrict__ sexp_w, const float* __restrict__ sexp_b,
    const float* __restrict__ te_w1, const float* __restrict__ te_b1,
    float* __restrict__ psea, float* __restrict__ bias1)
{
  int s = blockIdx.x, t = threadIdx.x;
  float ts = (float)s;
  float se = sinf(((ts * 2.0f) * 3.14159274101257324f) / 24.0f);
  __shared__ float l1[256], l2[256];
  l1[t] = fmaxf(se * se_w1[t] + se_b1[t], 0.f);
  __syncthreads();
  {
    float a = se_b2[t];
    const float* wr = se_w2 + (size_t)t * 256;
    for (int i = 0; i < 256; ++i) a += l1[i] * wr[i];
    l2[t] = a;
  }
  __syncthreads();
#pragma unroll
  for (int r = 0; r < 4; ++r) {
    int h = r * 256 + t;
    float v = sexp_b[h];
    const float* wr = sexp_w + (size_t)h * 256;
    for (int j = 0; j < 256; ++j) v += l2[j] * wr[j];
    psea[s * Hh + h] = pos_emb[s * Hh + h] + v;
    bias1[s * Hh + h] = te_b1[h] + ts * te_w1[(size_t)h * 1026 + 1024]
                                 + se * te_w1[(size_t)h * 1026 + 1025];
  }
}

// ---------------- softmax over score rows; writes split P in place --------
__global__ __launch_bounds__(256) void softmax2_k(float* __restrict__ S)
{
  int row = blockIdx.x * 4 + (threadIdx.x >> 6);
  int lane = threadIdx.x & 63;
  float* p = S + (size_t)row * 512;
  float4 a = *(float4*)&p[lane * 4];
  float4 b = *(float4*)&p[256 + lane * 4];
  float m = fmaxf(fmaxf(fmaxf(a.x, a.y), fmaxf(a.z, a.w)),
                  fmaxf(fmaxf(b.x, b.y), fmaxf(b.z, b.w)));
#pragma unroll
  for (int off = 32; off; off >>= 1) m = fmaxf(m, __shfl_xor(m, off));
  a.x = expf(a.x - m); a.y = expf(a.y - m); a.z = expf(a.z - m); a.w = expf(a.w - m);
  b.x = expf(b.x - m); b.y = expf(b.y - m); b.z = expf(b.z - m); b.w = expf(b.w - m);
  float s = a.x + a.y + a.z + a.w + b.x + b.y + b.z + b.w;
#pragma unroll
  for (int off = 32; off; off >>= 1) s += __shfl_xor(s, off);
  float inv = 1.f / s;
  a.x *= inv; a.y *= inv; a.z *= inv; a.w *= inv;
  b.x *= inv; b.y *= inv; b.z *= inv; b.w *= inv;
  ushort* u = (ushort*)S + (size_t)row * 1024;    // [hi 512 | lo 512]
  ushort4 ha, la, hb, lb;
  ha.x = f2bf(a.x); la.x = f2bf(a.x - bf2f(ha.x));
  ha.y = f2bf(a.y); la.y = f2bf(a.y - bf2f(ha.y));
  ha.z = f2bf(a.z); la.z = f2bf(a.z - bf2f(ha.z));
  ha.w = f2bf(a.w); la.w = f2bf(a.w - bf2f(ha.w));
  hb.x = f2bf(b.x); lb.x = f2bf(b.x - bf2f(hb.x));
  hb.y = f2bf(b.y); lb.y = f2bf(b.y - bf2f(hb.y));
  hb.z = f2bf(b.z); lb.z = f2bf(b.z - bf2f(hb.z));
  hb.w = f2bf(b.w); lb.w = f2bf(b.w - bf2f(hb.w));
  *(ushort4*)&u[lane * 4] = ha;
  *(ushort4*)&u[512 + lane * 4] = la;
  *(ushort4*)&u[256 + lane * 4] = hb;
  *(ushort4*)&u[768 + lane * 4] = lb;
}

// ---------------- logits = h1 @ tr_w2^T + b  (N=8, fp32 VALU) ----------
__global__ __launch_bounds__(256) void tr2_k(
    const float* __restrict__ h1, const float* __restrict__ w,
    const float* __restrict__ bias, float* __restrict__ logits)
{
  int wid = threadIdx.x >> 6, lane = threadIdx.x & 63;
  int t = blockIdx.x * 4 + wid;
  const float* x = h1 + (size_t)t * Hh;
  float acc[8];
#pragma unroll
  for (int e = 0; e < 8; ++e) acc[e] = 0.f;
  for (int k = lane; k < Hh; k += 64) {
    float xv = x[k];
#pragma unroll
    for (int e = 0; e < 8; ++e) acc[e] += xv * w[e * Hh + k];
  }
#pragma unroll
  for (int e = 0; e < 8; ++e) {
#pragma unroll
    for (int off = 32; off; off >>= 1) acc[e] += __shfl_xor(acc[e], off);
  }
  if (lane == 0) {
#pragma unroll
    for (int e = 0; e < 8; ++e) logits[(size_t)t * 8 + e] = acc[e] + bias[e];
  }
}

// ---------------- zero fill of dispatch+combine ----------------
__global__ __launch_bounds__(256) void fill0_k(float4* __restrict__ p, long long n4)
{
  long long i = (long long)blockIdx.x * 256 + threadIdx.x;
  long long stride = (long long)gridDim.x * 256;
  float4 z = make_float4(0.f, 0.f, 0.f, 0.f);
  for (; i < n4; i += stride) p[i] = z;
}

// ---------------- router: softmax, top2, slot writes, partial p-sums -------
__global__ __launch_bounds__(256) void router_k(
    float* __restrict__ out, float* __restrict__ partials)
{
  int t = blockIdx.x * 256 + threadIdx.x;            // token 0..4095
  float* lg = out + 100663296 + (size_t)t * 8;       // logits (in-place -> probs)
  float p[8];
#pragma unroll
  for (int e = 0; e < 8; ++e) p[e] = lg[e];
  float m = p[0];
#pragma unroll
  for (int e = 1; e < 8; ++e) m = fmaxf(m, p[e]);
  float s = 0.f;
#pragma unroll
  for (int e = 0; e < 8; ++e) { p[e] = expf(p[e] - m); s += p[e]; }
  float inv = 1.f / s;
#pragma unroll
  for (int e = 0; e < 8; ++e) p[e] *= inv;
#pragma unroll
  for (int e = 0; e < 8; ++e) lg[e] = p[e];          // router_probs out

  int i0 = 0; float v0 = p[0];
#pragma unroll
  for (int e = 1; e < 8; ++e) if (p[e] > v0) { v0 = p[e]; i0 = e; }
  int i1 = -1; float v1 = -1.f;
#pragma unroll
  for (int e = 0; e < 8; ++e) if (e != i0 && p[e] > v1) { v1 = p[e]; i1 = e; }
  float wn = 1.f / (v0 + v1);
  size_t db = (size_t)t * (8 * 1536);
  out[db + (size_t)i0 * 1536] = 1.f;
  out[db + (size_t)i1 * 1536] = 1.f;
  out[50331648 + db + (size_t)i0 * 1536] = v0 * wn;
  out[50331648 + db + (size_t)i1 * 1536] = v1 * wn;

  __shared__ float red[256];
#pragma unroll
  for (int e = 0; e < 8; ++e) {
    red[threadIdx.x] = p[e];
    __syncthreads();
    for (int st = 128; st; st >>= 1) {
      if (threadIdx.x < st) red[threadIdx.x] += red[threadIdx.x + st];
      __syncthreads();
    }
    if (threadIdx.x == 0) partials[blockIdx.x * 8 + e] = red[0];
    __syncthreads();
  }
}

// ---------------- aux loss + cleanup of partials scratch ----------------
__global__ __launch_bounds__(64) void aux_k(float* __restrict__ partials,
                                            float* __restrict__ out)
{
  int lane = threadIdx.x;
  float v = 0.f;
  if (lane < 8) {
    float s = 0.f;
    for (int b = 0; b < 16; ++b) s += partials[b * 8 + lane];
    float pm = s / 4096.f;
    v = pm * logf(pm * 8.f + 1e-9f);
  }
#pragma unroll
  for (int off = 4; off; off >>= 1) v += __shfl_xor(v, off);
  if (lane == 0) out[100696064] = v;
  partials[lane] = 0.f;
  partials[64 + lane] = 0.f;
}

extern "C" void kernel_launch(void* const* d_in, const int* in_sizes, int n_in,
                              void* d_out, int out_size, void* d_ws, size_t ws_size,
                              hipStream_t stream)
{
  const float* hidden = (const float*)d_in[0];
  const float* pos_emb = (const float*)d_in[1];
  const float* se_w1 = (const float*)d_in[2];
  const float* se_b1 = (const float*)d_in[3];
  const float* se_w2 = (const float*)d_in[4];
  const float* se_b2 = (const float*)d_in[5];
  const float* sexp_w = (const float*)d_in[6];
  const float* sexp_b = (const float*)d_in[7];
  const float* te_w1 = (const float*)d_in[8];
  const float* te_b1 = (const float*)d_in[9];
  const float* te_w2 = (const float*)d_in[10];
  const float* te_b2 = (const float*)d_in[11];
  const float* ain_w = (const float*)d_in[12];
  const float* ain_b = (const float*)d_in[13];
  const float* aout_w = (const float*)d_in[14];
  const float* aout_b = (const float*)d_in[15];
  const float* tr_w1 = (const float*)d_in[16];
  const float* tr_b1 = (const float*)d_in[17];
  const float* tr_w2 = (const float*)d_in[18];
  const float* tr_b2 = (const float*)d_in[19];
  float* out = (float*)d_out;

  // scratch arena: byte offsets inside d_out's dispatch+combine region (402MB)
  char* arena = (char*)d_out;
  ushort* W1    = (ushort*)(arena + 0);          // te_w1 hi|lo  [1024][2048]
  ushort* W2h   = (ushort*)(arena + 4194304);    // te_w2
  ushort* Wa    = (ushort*)(arena + 8388608);    // attn_in [3072][2048]
  ushort* Wo    = (ushort*)(arena + 20971520);   // attn_out
  ushort* Wt    = (ushort*)(arena + 25165824);   // tr_w1
  ushort* hid2  = (ushort*)(arena + 29360128);   // hidden   [4096][2048]
  ushort* enc1  = (ushort*)(arena + 46137344);   // [4096][2048]
  ushort* enc2  = (ushort*)(arena + 62914560);   // [4096][2048]
  ushort* qkv2  = (ushort*)(arena + 79691776);   // [4096][6144] hi|lo of qkv
  float*  scor  = (float*)(arena + 130023424);   // [64][512][512] -> split P in place
  ushort* attno = (ushort*)(arena + 197132288);  // [4096][2048]
  ushort* encf  = (ushort*)(arena + 213909504);  // [4096][2048]
  float*  h1    = (float*)(arena + 230686720);   // [4096][1024] fp32
  float*  psea  = (float*)(arena + 247463936);   // [512][1024]
  float*  bias1 = (float*)(arena + 249561088);   // [512][1024]
  float*  parts = out + 51380224;                // [16][8], zeroed by aux_k
  float*  lgts  = out + 100663296;               // logits -> probs region

  // weight / input hi-lo expansions
  convert_k<<<1024, 256, 0, stream>>>(te_w1, 1026, W1, 1024);
  convert_k<<<1024, 256, 0, stream>>>(te_w2, 1024, W2h, 1024);
  convert_k<<<3072, 256, 0, stream>>>(ain_w, 1024, Wa, 1024);
  convert_k<<<1024, 256, 0, stream>>>(aout_w, 1024, Wo, 1024);
  convert_k<<<1024, 256, 0, stream>>>(tr_w1, 1024, Wt, 1024);
  convert_k<<<4096, 256, 0, stream>>>(hidden, 1024, hid2, 1024);

  precompute_k<<<512, 256, 0, stream>>>(pos_emb, se_w1, se_b1, se_w2, se_b2,
                                        sexp_w, sexp_b, te_w1, te_b1, psea, bias1);

  // G1: enc1 = relu(hidden @ te_w1'^T + bias1[s])  (split out)
  mgemm_k<false, 1, true, false, true><<<dim3(8, 32, 1), 256, 0, stream>>>(
      hid2, 2048, 0, 0, 0, 1024,
      W1, 2048, 0, 0, 0, 1024,
      nullptr, enc1, 2048, 0, 0, 1024,
      1024, 1, nullptr, bias1, 1024, 512, 1.f);

  // G2: enc2 = enc1 @ te_w2^T + te_b2 + psea[s]  (split out)
  mgemm_k<false, 1, false, true, true><<<dim3(8, 32, 1), 256, 0, stream>>>(
      enc1, 2048, 0, 0, 0, 1024,
      W2h, 2048, 0, 0, 0, 1024,
      nullptr, enc2, 2048, 0, 0, 1024,
      1024, 1, te_b2, psea, 1024, 512, 1.f);

  // G3: qkv = enc2 @ attn_in_w^T + attn_in_b  (split out, [4096][3072|3072])
  mgemm_k<false, 1, false, true, false><<<dim3(24, 32, 1), 256, 0, stream>>>(
      enc2, 2048, 0, 0, 0, 1024,
      Wa, 2048, 0, 0, 0, 1024,
      nullptr, qkv2, 6144, 0, 0, 3072,
      1024, 1, ain_b, nullptr, 1, 1, 1.f);

  // G4: scores[b,h] = Q K^T / sqrt(128)  (fp32 out)
  mgemm_k<false, 0, false, false, false><<<dim3(4, 4, 64), 256, 0, stream>>>(
      qkv2, 6144, 3145728, 128, 0, 3072,
      qkv2, 6144, 3145728, 128, 1024, 4096,
      scor, nullptr, 512, 2097152, 262144,
      0, 128, 8, nullptr, nullptr, 1, 1, 0.08838834764831845f);

  softmax2_k<<<8192, 256, 0, stream>>>(scor);

  // G5: attno[b,h] = P @ V  (A = split P in scor, B = V rows k-major, split out)
  mgemm_k<true, 1, false, false, false><<<dim3(1, 4, 64), 256, 0, stream>>>(
      (const ushort*)scor, 1024, 4194304, 524288, 0, 512,
      qkv2, 6144, 3145728, 128, 2048, 5120,
      nullptr, attno, 2048, 1048576, 128,
      1024, 512, 8, nullptr, nullptr, 1, 1, 1.f);

  // G6: encf = attno @ attn_out_w^T + attn_out_b  (split out)
  mgemm_k<false, 1, false, true, false><<<dim3(8, 32, 1), 256, 0, stream>>>(
      attno, 2048, 0, 0, 0, 1024,
      Wo, 2048, 0, 0, 0, 1024,
      nullptr, encf, 2048, 0, 0, 1024,
      1024, 1, aout_b, nullptr, 1, 1, 1.f);

  // G7: h1 = relu(encf @ tr_w1^T + tr_b1)  (fp32 out)
  mgemm_k<false, 0, true, true, false><<<dim3(8, 32, 1), 256, 0, stream>>>(
      encf, 2048, 0, 0, 0, 1024,
      Wt, 2048, 0, 0, 0, 1024,
      h1, nullptr, 1024, 0, 0, 0,
      1024, 1, tr_b1, nullptr, 1, 1, 1.f);

  tr2_k<<<1024, 256, 0, stream>>>(h1, tr_w2, tr_b2, lgts);

  // zero dispatch+combine (wipes all arena scratch)
  fill0_k<<<4096, 256, 0, stream>>>((float4*)out, 25165824LL);

  router_k<<<16, 256, 0, stream>>>(out, parts);
  aux_k<<<1, 64, 0, stream>>>(parts, out);
}

// Round 4
// 527.595 us; speedup vs baseline: 2.4789x; 1.9816x over previous
//
#include <hip/hip_runtime.h>
#include <hip/hip_bf16.h>

// TimeMoERouter: B=8 S=512 H=1024 E=8 TOPK=2 NHEADS=8 DH=128 CAP=1536
// Round 4: split-precision MFMA GEMM with T3-minimum 2-phase pipeline:
//  - reg-staged, DOUBLE-buffered swizzled LDS (BK=32, one barrier per k-step,
//    next-tile global loads in flight across the MFMA phase)
//  - vtrans_k pre-transposes V so PV is a standard GEMM (no scalar scatter)
//  - LDS-bounce coalesced epilogues for both fp32 and split-bf16 C
// d_out (402MB dispatch+combine region) is the scratch arena; fill0 re-zeroes it.

#define Hh 1024

typedef __attribute__((ext_vector_type(8))) short short8v;
typedef __attribute__((ext_vector_type(4))) float f32x4;

static __device__ __forceinline__ ushort f2bf(float x) {
  uint u = __float_as_uint(x);
  u += 0x7FFF + ((u >> 16) & 1);          // round-to-nearest-even
  return (ushort)(u >> 16);
}
static __device__ __forceinline__ float bf2f(ushort h) {
  return __uint_as_float(((uint)h) << 16);
}

// ---------------- split-precision MFMA GEMM ----------------
// C[m,n] = alpha * sum_k A[m,k]*B[n,k] over segments (aHi,bHi)+(aHi,bLo)+(aLo,bHi).
// A: bf16 buffer, row stride lda, hi at col aHi+k, lo at col aLo+k.
// B: [N][*] weight-style rows, hi at bHi+k, lo at bLo+k.
// EPI: 0 = fp32 C; 1 = split bf16 (hi at col n, lo at col n+splitOff).
// Tile 128x128, BK=32, 4 waves (2x2), 16x16x32 bf16 MFMA.
// LDS: two 32KB buffers, each {Ah,Al,Bh,Bl}[128][32] ush, XOR-swizzled.
template<int EPI, bool RELU, bool HAS_BN, bool HAS_BSN>
__global__ __launch_bounds__(256) void mgemm_k(
    const ushort* __restrict__ A, int lda, long long sAmaj, long long sAmin, int aHi, int aLo,
    const ushort* __restrict__ B, int ldb, long long sBmaj, long long sBmin, int bHi, int bLo,
    float* __restrict__ Cf, ushort* __restrict__ Ch, int ldc, long long sCmaj, long long sCmin,
    int splitOff, int Kd, int zdiv,
    const float* __restrict__ bN, const float* __restrict__ bSN, int ldbs, int smod,
    float alpha)
{
  // XCD-aware bijective swizzle (all grids are multiples of 8)
  int gx = gridDim.x, gy = gridDim.y;
  int lin = (blockIdx.z * gy + blockIdx.y) * gx + blockIdx.x;
  int nwg = gx * gy * gridDim.z;
  int cpx = nwg >> 3;
  int swz = (lin & 7) * cpx + (lin >> 3);
  int bz = swz / (gx * gy);
  int rem = swz - bz * (gx * gy);
  int by = rem / gx, bx = rem - by * gx;

  int zj = bz / zdiv, zi = bz - zj * zdiv;
  A += (size_t)zj * sAmaj + (size_t)zi * sAmin;
  B += (size_t)zj * sBmaj + (size_t)zi * sBmin;
  long long coff = (long long)zj * sCmaj + (long long)zi * sCmin;

  int m0 = by * 128, n0 = bx * 128;

  __shared__ __align__(16) ushort smem[32768];   // 64 KB = 2 x 32KB buffers
  // buffer layout (bytes, within each 32768-B buffer):
  //   Ah [0,8192) Al [8192,16384) Bh [16384,24576) Bl [24576,32768)

  int t = threadIdx.x;
  int l = t & 63, w = t >> 6;
  int wm = w >> 1, wn = w & 1;

  f32x4 acc[4][4];
#pragma unroll
  for (int i = 0; i < 4; ++i)
#pragma unroll
    for (int j = 0; j < 4; ++j) acc[i][j] = (f32x4){0.f, 0.f, 0.f, 0.f};

  // staging: thread covers row srow, int4-slots {sc, sc+1} of 4 (32 ush = 4 slots)
  int srow = t >> 1;
  int sc = (t & 1) * 2;
  const ushort* gAh = A + (size_t)(m0 + srow) * lda + aHi + sc * 8;
  const ushort* gAl = A + (size_t)(m0 + srow) * lda + aLo + sc * 8;
  const ushort* gBh = B + (size_t)(n0 + srow) * ldb + bHi + sc * 8;
  const ushort* gBl = B + (size_t)(n0 + srow) * ldb + bLo + sc * 8;
  int wsw = ((srow >> 1) & 7) << 4;
  int wo0 = (srow * 64 + sc * 16) ^ wsw;
  int wo1 = (srow * 64 + sc * 16 + 16) ^ wsw;

  // fragment read offsets (within a tile)
  int aoff[4], boff[4];
#pragma unroll
  for (int mi = 0; mi < 4; ++mi) {
    int row = wm * 64 + mi * 16 + (l & 15);
    aoff[mi] = (row * 64 + (l >> 4) * 16) ^ (((row >> 1) & 7) << 4);
  }
#pragma unroll
  for (int ni = 0; ni < 4; ++ni) {
    int row = wn * 64 + ni * 16 + (l & 15);
    boff[ni] = (row * 64 + (l >> 4) * 16) ^ (((row >> 1) & 7) << 4);
  }

  int4 rAh0, rAh1, rAl0, rAl1, rBh0, rBh1, rBl0, rBl1;
#define LOADK(kc) do { \
    rAh0 = *(const int4*)(gAh + (kc));  rAh1 = *(const int4*)(gAh + (kc) + 8); \
    rAl0 = *(const int4*)(gAl + (kc));  rAl1 = *(const int4*)(gAl + (kc) + 8); \
    rBh0 = *(const int4*)(gBh + (kc));  rBh1 = *(const int4*)(gBh + (kc) + 8); \
    rBl0 = *(const int4*)(gBl + (kc));  rBl1 = *(const int4*)(gBl + (kc) + 8); \
  } while (0)
#define STOREK(bufbase) do { \
    char* nb_ = (char*)smem + (bufbase); \
    *(int4*)(nb_ + wo0) = rAh0;          *(int4*)(nb_ + wo1) = rAh1; \
    *(int4*)(nb_ + 8192 + wo0) = rAl0;   *(int4*)(nb_ + 8192 + wo1) = rAl1; \
    *(int4*)(nb_ + 16384 + wo0) = rBh0;  *(int4*)(nb_ + 16384 + wo1) = rBh1; \
    *(int4*)(nb_ + 24576 + wo0) = rBl0;  *(int4*)(nb_ + 24576 + wo1) = rBl1; \
  } while (0)

  int nt = Kd >> 5;
  LOADK(0);
  STOREK(0);
  __syncthreads();
  int cur = 0;
  for (int s2 = 0; s2 < nt; ++s2) {
    bool more = (s2 + 1 < nt);
    if (more) LOADK((s2 + 1) * 32);      // loads in flight across MFMA phase
    char* base = (char*)smem + cur * 32768;
    short8v ah[4], al[4], bb[4];
#pragma unroll
    for (int mi = 0; mi < 4; ++mi) ah[mi] = *(const short8v*)(base + aoff[mi]);
#pragma unroll
    for (int mi = 0; mi < 4; ++mi) al[mi] = *(const short8v*)(base + 8192 + aoff[mi]);
#pragma unroll
    for (int ni = 0; ni < 4; ++ni) bb[ni] = *(const short8v*)(base + 16384 + boff[ni]);
#pragma unroll
    for (int mi = 0; mi < 4; ++mi)
#pragma unroll
      for (int ni = 0; ni < 4; ++ni)
        acc[mi][ni] = __builtin_amdgcn_mfma_f32_16x16x32_bf16(ah[mi], bb[ni], acc[mi][ni], 0, 0, 0);
#pragma unroll
    for (int mi = 0; mi < 4; ++mi)
#pragma unroll
      for (int ni = 0; ni < 4; ++ni)
        acc[mi][ni] = __builtin_amdgcn_mfma_f32_16x16x32_bf16(al[mi], bb[ni], acc[mi][ni], 0, 0, 0);
#pragma unroll
    for (int ni = 0; ni < 4; ++ni) bb[ni] = *(const short8v*)(base + 24576 + boff[ni]);
#pragma unroll
    for (int mi = 0; mi < 4; ++mi)
#pragma unroll
      for (int ni = 0; ni < 4; ++ni)
        acc[mi][ni] = __builtin_amdgcn_mfma_f32_16x16x32_bf16(ah[mi], bb[ni], acc[mi][ni], 0, 0, 0);
    if (more) STOREK((cur ^ 1) * 32768); // vmcnt wait lands here, after MFMA
    __syncthreads();
    cur ^= 1;
  }
#undef LOADK
#undef STOREK

  // fold alpha + biases + relu into acc
#pragma unroll
  for (int mi = 0; mi < 4; ++mi)
#pragma unroll
    for (int j = 0; j < 4; ++j) {
      int m = m0 + wm * 64 + mi * 16 + (l >> 4) * 4 + j;
#pragma unroll
      for (int ni = 0; ni < 4; ++ni) {
        int n = n0 + wn * 64 + ni * 16 + (l & 15);
        float x = acc[mi][ni][j] * alpha;
        if (HAS_BN) x += bN[n];
        if (HAS_BSN) x += bSN[(size_t)(m % smod) * ldbs + n];
        if (RELU) x = fmaxf(x, 0.f);
        acc[mi][ni][j] = x;
      }
    }

  if (EPI == 0) {
    // fp32 LDS-bounce: two 64-row passes, coalesced int4 stores
    float* Fs = (float*)smem;
#pragma unroll
    for (int p = 0; p < 2; ++p) {
      __syncthreads();
      if (wm == p) {
#pragma unroll
        for (int mi = 0; mi < 4; ++mi)
#pragma unroll
          for (int j = 0; j < 4; ++j) {
            int r = mi * 16 + (l >> 4) * 4 + j;
#pragma unroll
            for (int ni = 0; ni < 4; ++ni) {
              int c = wn * 64 + ni * 16 + (l & 15);
              *(float*)((char*)Fs + ((r * 512 + c * 4) ^ ((r & 7) << 4))) = acc[mi][ni][j];
            }
          }
      }
      __syncthreads();
#pragma unroll
      for (int r8 = 0; r8 < 8; ++r8) {
        int idx = r8 * 256 + t;
        int row = idx >> 5, slot = idx & 31;
        int4 v = *(const int4*)((char*)Fs + ((row * 512 + slot * 16) ^ ((row & 7) << 4)));
        *(int4*)(Cf + coff + (size_t)(m0 + p * 64 + row) * ldc + n0 + slot * 4) = v;
      }
    }
  } else {
    // split-bf16 LDS-bounce: hi pass then lo pass, coalesced int4 stores
    __syncthreads();
    ushort* Es = smem;                     // [128][128] ushort = 32KB
#pragma unroll
    for (int pass = 0; pass < 2; ++pass) {
#pragma unroll
      for (int mi = 0; mi < 4; ++mi)
#pragma unroll
        for (int j = 0; j < 4; ++j) {
          int lr = wm * 64 + mi * 16 + (l >> 4) * 4 + j;
#pragma unroll
          for (int ni = 0; ni < 4; ++ni) {
            int lcb = (wn * 64 + ni * 16 + (l & 15)) * 2;
            float x = acc[mi][ni][j];
            ushort h = f2bf(x);
            ushort vv = (pass == 0) ? h : f2bf(x - bf2f(h));
            *(ushort*)((char*)Es + ((lr * 256 + lcb) ^ ((lr & 7) << 4))) = vv;
          }
        }
      __syncthreads();
      int off = (pass == 0) ? 0 : splitOff;
#pragma unroll
      for (int r = 0; r < 8; ++r) {
        int idx = r * 256 + t;
        int row = idx >> 4, cb = (idx & 15) * 16;
        int4 v = *(const int4*)((char*)Es + ((row * 256 + cb) ^ ((row & 7) << 4)));
        *(int4*)((char*)(Ch + coff + (size_t)(m0 + row) * ldc + off + n0) + cb) = v;
      }
      if (pass == 0) __syncthreads();
    }
  }
}

// ---------------- V transpose: qkv2 V part -> Vt[bh][128 d][512 hi|512 lo] ----
__global__ __launch_bounds__(256) void vtrans_k(
    const ushort* __restrict__ qkv2, ushort* __restrict__ Vt)
{
  int kt = blockIdx.x;        // 0..3 (128-k tiles)
  int bh = blockIdx.y;        // 0..63
  int b = bh >> 3, h = bh & 7;
  __shared__ ushort VT[16384];  // [128 d][128 k], k-index XOR-permuted by (d>>3)
  int t = threadIdx.x;
#pragma unroll
  for (int seg = 0; seg < 2; ++seg) {
    int csrc = 2048 + h * 128 + seg * 3072;
    if (seg) __syncthreads();
#pragma unroll
    for (int r = 0; r < 8; ++r) {
      int idx = r * 256 + t;
      int k = idx >> 4, ds = idx & 15;
      int4 v = *(const int4*)(qkv2 + (size_t)(b * 512 + kt * 128 + k) * 6144 + csrc + ds * 8);
      ushort tmp[8];
      *(int4*)tmp = v;
#pragma unroll
      for (int j = 0; j < 8; ++j) {
        int d = ds * 8 + j;
        VT[d * 128 + (k ^ ((d >> 3) << 3))] = tmp[j];
      }
    }
    __syncthreads();
#pragma unroll
    for (int r = 0; r < 8; ++r) {
      int idx = r * 256 + t;
      int d = idx >> 4, os = idx & 15;
      int slot = os ^ (d >> 3);
      int4 v = *(const int4*)(VT + d * 128 + slot * 8);
      *(int4*)(Vt + (size_t)bh * 131072 + (size_t)d * 1024 + seg * 512 + kt * 128 + os * 8) = v;
    }
  }
}

// ---------------- fp32 [N][K] -> bf16 hi|lo [N][2K] ----------------
__global__ __launch_bounds__(256) void convert_k(
    const float* __restrict__ W, int lda, ushort* __restrict__ Whl, int K)
{
  int r = blockIdx.x;
  int c = threadIdx.x * 4;
  const float* src = W + (size_t)r * lda + c;
  float x0 = src[0], x1 = src[1], x2 = src[2], x3 = src[3];
  ushort4 h, lo;
  h.x = f2bf(x0); lo.x = f2bf(x0 - bf2f(h.x));
  h.y = f2bf(x1); lo.y = f2bf(x1 - bf2f(h.y));
  h.z = f2bf(x2); lo.z = f2bf(x2 - bf2f(h.z));
  h.w = f2bf(x3); lo.w = f2bf(x3 - bf2f(h.w));
  ushort* dst = Whl + (size_t)r * 2 * K;
  *(ushort4*)&dst[c] = h;
  *(ushort4*)&dst[K + c] = lo;
}

// ---------------- seasonal / positional precompute (fp32) ----------------
__global__ __launch_bounds__(256) void precompute_k(
    const float* __restrict__ pos_emb,
    const float* __restrict__ se_w1, const float* __restrict__ se_b1,
    const float* __restrict__ se_w2, const float* __restrict__ se_b2,
    const float* __restrict__ sexp_w, const float* __restrict__ sexp_b,
    const float* __restrict__ te_w1, const float* __restrict__ te_b1,
    float* __restrict__ psea, float* __restrict__ bias1)
{
  int s = blockIdx.x, t = threadIdx.x;
  float ts = (float)s;
  float se = sinf(((ts * 2.0f) * 3.14159274101257324f) / 24.0f);
  __shared__ float l1[256], l2[256];
  l1[t] = fmaxf(se * se_w1[t] + se_b1[t], 0.f);
  __syncthreads();
  {
    float a = se_b2[t];
    const float* wr = se_w2 + (size_t)t * 256;
    for (int i = 0; i < 256; ++i) a += l1[i] * wr[i];
    l2[t] = a;
  }
  __syncthreads();
#pragma unroll
  for (int r = 0; r < 4; ++r) {
    int h = r * 256 + t;
    float v = sexp_b[h];
    const float* wr = sexp_w + (size_t)h * 256;
    for (int j = 0; j < 256; ++j) v += l2[j] * wr[j];
    psea[s * Hh + h] = pos_emb[s * Hh + h] + v;
    bias1[s * Hh + h] = te_b1[h] + ts * te_w1[(size_t)h * 1026 + 1024]
                                 + se * te_w1[(size_t)h * 1026 + 1025];
  }
}

// ---------------- softmax over score rows; writes split P in place --------
__global__ __launch_bounds__(256) void softmax2_k(float* __restrict__ S)
{
  int row = blockIdx.x * 4 + (threadIdx.x >> 6);
  int lane = threadIdx.x & 63;
  float* p = S + (size_t)row * 512;
  float4 a = *(float4*)&p[lane * 4];
  float4 b = *(float4*)&p[256 + lane * 4];
  float m = fmaxf(fmaxf(fmaxf(a.x, a.y), fmaxf(a.z, a.w)),
                  fmaxf(fmaxf(b.x, b.y), fmaxf(b.z, b.w)));
#pragma unroll
  for (int off = 32; off; off >>= 1) m = fmaxf(m, __shfl_xor(m, off));
  a.x = expf(a.x - m); a.y = expf(a.y - m); a.z = expf(a.z - m); a.w = expf(a.w - m);
  b.x = expf(b.x - m); b.y = expf(b.y - m); b.z = expf(b.z - m); b.w = expf(b.w - m);
  float s = a.x + a.y + a.z + a.w + b.x + b.y + b.z + b.w;
#pragma unroll
  for (int off = 32; off; off >>= 1) s += __shfl_xor(s, off);
  float inv = 1.f / s;
  a.x *= inv; a.y *= inv; a.z *= inv; a.w *= inv;
  b.x *= inv; b.y *= inv; b.z *= inv; b.w *= inv;
  ushort* u = (ushort*)S + (size_t)row * 1024;    // [hi 512 | lo 512]
  ushort4 ha, la, hb, lb;
  ha.x = f2bf(a.x); la.x = f2bf(a.x - bf2f(ha.x));
  ha.y = f2bf(a.y); la.y = f2bf(a.y - bf2f(ha.y));
  ha.z = f2bf(a.z); la.z = f2bf(a.z - bf2f(ha.z));
  ha.w = f2bf(a.w); la.w = f2bf(a.w - bf2f(ha.w));
  hb.x = f2bf(b.x); lb.x = f2bf(b.x - bf2f(hb.x));
  hb.y = f2bf(b.y); lb.y = f2bf(b.y - bf2f(hb.y));
  hb.z = f2bf(b.z); lb.z = f2bf(b.z - bf2f(hb.z));
  hb.w = f2bf(b.w); lb.w = f2bf(b.w - bf2f(hb.w));
  *(ushort4*)&u[lane * 4] = ha;
  *(ushort4*)&u[512 + lane * 4] = la;
  *(ushort4*)&u[256 + lane * 4] = hb;
  *(ushort4*)&u[768 + lane * 4] = lb;
}

// ---------------- logits = h1 @ tr_w2^T + b  (N=8, fp32 VALU) ----------
__global__ __launch_bounds__(256) void tr2_k(
    const float* __restrict__ h1, const float* __restrict__ w,
    const float* __restrict__ bias, float* __restrict__ logits)
{
  int wid = threadIdx.x >> 6, lane = threadIdx.x & 63;
  int t = blockIdx.x * 4 + wid;
  const float* x = h1 + (size_t)t * Hh;
  float acc[8];
#pragma unroll
  for (int e = 0; e < 8; ++e) acc[e] = 0.f;
  for (int k = lane; k < Hh; k += 64) {
    float xv = x[k];
#pragma unroll
    for (int e = 0; e < 8; ++e) acc[e] += xv * w[e * Hh + k];
  }
#pragma unroll
  for (int e = 0; e < 8; ++e) {
#pragma unroll
    for (int off = 32; off; off >>= 1) acc[e] += __shfl_xor(acc[e], off);
  }
  if (lane == 0) {
#pragma unroll
    for (int e = 0; e < 8; ++e) logits[(size_t)t * 8 + e] = acc[e] + bias[e];
  }
}

// ---------------- zero fill of dispatch+combine ----------------
__global__ __launch_bounds__(256) void fill0_k(float4* __restrict__ p, long long n4)
{
  long long i = (long long)blockIdx.x * 256 + threadIdx.x;
  long long stride = (long long)gridDim.x * 256;
  float4 z = make_float4(0.f, 0.f, 0.f, 0.f);
  for (; i < n4; i += stride) p[i] = z;
}

// ---------------- router: softmax, top2, slot writes, partial p-sums -------
__global__ __launch_bounds__(256) void router_k(
    float* __restrict__ out, float* __restrict__ partials)
{
  int t = blockIdx.x * 256 + threadIdx.x;            // token 0..4095
  float* lg = out + 100663296 + (size_t)t * 8;       // logits (in-place -> probs)
  float p[8];
#pragma unroll
  for (int e = 0; e < 8; ++e) p[e] = lg[e];
  float m = p[0];
#pragma unroll
  for (int e = 1; e < 8; ++e) m = fmaxf(m, p[e]);
  float s = 0.f;
#pragma unroll
  for (int e = 0; e < 8; ++e) { p[e] = expf(p[e] - m); s += p[e]; }
  float inv = 1.f / s;
#pragma unroll
  for (int e = 0; e < 8; ++e) p[e] *= inv;
#pragma unroll
  for (int e = 0; e < 8; ++e) lg[e] = p[e];          // router_probs out

  int i0 = 0; float v0 = p[0];
#pragma unroll
  for (int e = 1; e < 8; ++e) if (p[e] > v0) { v0 = p[e]; i0 = e; }
  int i1 = -1; float v1 = -1.f;
#pragma unroll
  for (int e = 0; e < 8; ++e) if (e != i0 && p[e] > v1) { v1 = p[e]; i1 = e; }
  float wn = 1.f / (v0 + v1);
  size_t db = (size_t)t * (8 * 1536);
  out[db + (size_t)i0 * 1536] = 1.f;
  out[db + (size_t)i1 * 1536] = 1.f;
  out[50331648 + db + (size_t)i0 * 1536] = v0 * wn;
  out[50331648 + db + (size_t)i1 * 1536] = v1 * wn;

  __shared__ float red[256];
#pragma unroll
  for (int e = 0; e < 8; ++e) {
    red[threadIdx.x] = p[e];
    __syncthreads();
    for (int st = 128; st; st >>= 1) {
      if (threadIdx.x < st) red[threadIdx.x] += red[threadIdx.x + st];
      __syncthreads();
    }
    if (threadIdx.x == 0) partials[blockIdx.x * 8 + e] = red[0];
    __syncthreads();
  }
}

// ---------------- aux loss + cleanup of partials scratch ----------------
__global__ __launch_bounds__(64) void aux_k(float* __restrict__ partials,
                                            float* __restrict__ out)
{
  int lane = threadIdx.x;
  float v = 0.f;
  if (lane < 8) {
    float s = 0.f;
    for (int b = 0; b < 16; ++b) s += partials[b * 8 + lane];
    float pm = s / 4096.f;
    v = pm * logf(pm * 8.f + 1e-9f);
  }
#pragma unroll
  for (int off = 4; off; off >>= 1) v += __shfl_xor(v, off);
  if (lane == 0) out[100696064] = v;
  partials[lane] = 0.f;
  partials[64 + lane] = 0.f;
}

extern "C" void kernel_launch(void* const* d_in, const int* in_sizes, int n_in,
                              void* d_out, int out_size, void* d_ws, size_t ws_size,
                              hipStream_t stream)
{
  const float* hidden = (const float*)d_in[0];
  const float* pos_emb = (const float*)d_in[1];
  const float* se_w1 = (const float*)d_in[2];
  const float* se_b1 = (const float*)d_in[3];
  const float* se_w2 = (const float*)d_in[4];
  const float* se_b2 = (const float*)d_in[5];
  const float* sexp_w = (const float*)d_in[6];
  const float* sexp_b = (const float*)d_in[7];
  const float* te_w1 = (const float*)d_in[8];
  const float* te_b1 = (const float*)d_in[9];
  const float* te_w2 = (const float*)d_in[10];
  const float* te_b2 = (const float*)d_in[11];
  const float* ain_w = (const float*)d_in[12];
  const float* ain_b = (const float*)d_in[13];
  const float* aout_w = (const float*)d_in[14];
  const float* aout_b = (const float*)d_in[15];
  const float* tr_w1 = (const float*)d_in[16];
  const float* tr_b1 = (const float*)d_in[17];
  const float* tr_w2 = (const float*)d_in[18];
  const float* tr_b2 = (const float*)d_in[19];
  float* out = (float*)d_out;

  // scratch arena: byte offsets inside d_out's dispatch+combine region (402MB)
  char* arena = (char*)d_out;
  ushort* W1    = (ushort*)(arena + 0);          // te_w1 hi|lo  [1024][2048]
  ushort* W2h   = (ushort*)(arena + 4194304);    // te_w2
  ushort* Wa    = (ushort*)(arena + 8388608);    // attn_in [3072][2048]
  ushort* Wo    = (ushort*)(arena + 20971520);   // attn_out
  ushort* Wt    = (ushort*)(arena + 25165824);   // tr_w1
  ushort* hid2  = (ushort*)(arena + 29360128);   // hidden   [4096][2048]
  ushort* enc1  = (ushort*)(arena + 46137344);   // [4096][2048]
  ushort* enc2  = (ushort*)(arena + 62914560);   // [4096][2048]
  ushort* qkv2  = (ushort*)(arena + 79691776);   // [4096][6144] hi|lo of qkv
  float*  scor  = (float*)(arena + 130023424);   // [64][512][512] -> split P in place
  ushort* attno = (ushort*)(arena + 197132288);  // [4096][2048]
  ushort* encf  = (ushort*)(arena + 213909504);  // [4096][2048]
  float*  h1    = (float*)(arena + 230686720);   // [4096][1024] fp32
  float*  psea  = (float*)(arena + 247463936);   // [512][1024]
  float*  bias1 = (float*)(arena + 249561088);   // [512][1024]
  ushort* Vt    = (ushort*)(arena + 251658240);  // [64][128][1024] 16MB
  float*  parts = out + 51380224;                // [16][8], zeroed by aux_k
  float*  lgts  = out + 100663296;               // logits -> probs region

  // weight / input hi-lo expansions
  convert_k<<<1024, 256, 0, stream>>>(te_w1, 1026, W1, 1024);
  convert_k<<<1024, 256, 0, stream>>>(te_w2, 1024, W2h, 1024);
  convert_k<<<3072, 256, 0, stream>>>(ain_w, 1024, Wa, 1024);
  convert_k<<<1024, 256, 0, stream>>>(aout_w, 1024, Wo, 1024);
  convert_k<<<1024, 256, 0, stream>>>(tr_w1, 1024, Wt, 1024);
  convert_k<<<4096, 256, 0, stream>>>(hidden, 1024, hid2, 1024);

  precompute_k<<<512, 256, 0, stream>>>(pos_emb, se_w1, se_b1, se_w2, se_b2,
                                        sexp_w, sexp_b, te_w1, te_b1, psea, bias1);

  // G1: enc1 = relu(hidden @ te_w1'^T + bias1[s])  (split out)
  mgemm_k<1, true, false, true><<<dim3(8, 32, 1), 256, 0, stream>>>(
      hid2, 2048, 0, 0, 0, 1024,
      W1, 2048, 0, 0, 0, 1024,
      nullptr, enc1, 2048, 0, 0, 1024,
      1024, 1, nullptr, bias1, 1024, 512, 1.f);

  // G2: enc2 = enc1 @ te_w2^T + te_b2 + psea[s]  (split out)
  mgemm_k<1, false, true, true><<<dim3(8, 32, 1), 256, 0, stream>>>(
      enc1, 2048, 0, 0, 0, 1024,
      W2h, 2048, 0, 0, 0, 1024,
      nullptr, enc2, 2048, 0, 0, 1024,
      1024, 1, te_b2, psea, 1024, 512, 1.f);

  // G3: qkv = enc2 @ attn_in_w^T + attn_in_b  (split out, [4096][3072|3072])
  mgemm_k<1, false, true, false><<<dim3(24, 32, 1), 256, 0, stream>>>(
      enc2, 2048, 0, 0, 0, 1024,
      Wa, 2048, 0, 0, 0, 1024,
      nullptr, qkv2, 6144, 0, 0, 3072,
      1024, 1, ain_b, nullptr, 1, 1, 1.f);

  // G4: scores[b,h] = Q K^T / sqrt(128)  (fp32 out)
  mgemm_k<0, false, false, false><<<dim3(4, 4, 64), 256, 0, stream>>>(
      qkv2, 6144, 3145728, 128, 0, 3072,
      qkv2, 6144, 3145728, 128, 1024, 4096,
      scor, nullptr, 512, 2097152, 262144,
      0, 128, 8, nullptr, nullptr, 1, 1, 0.08838834764831845f);

  softmax2_k<<<8192, 256, 0, stream>>>(scor);

  // V pre-transpose for PV
  vtrans_k<<<dim3(4, 64), 256, 0, stream>>>(qkv2, Vt);

  // G5: attno[b,h] = P @ V  (A = split P, B = Vt weight-style, split out)
  mgemm_k<1, false, false, false><<<dim3(1, 4, 64), 256, 0, stream>>>(
      (const ushort*)scor, 1024, 4194304, 524288, 0, 512,
      Vt, 1024, 1048576, 131072, 0, 512,
      nullptr, attno, 2048, 1048576, 128,
      1024, 512, 8, nullptr, nullptr, 1, 1, 1.f);

  // G6: encf = attno @ attn_out_w^T + attn_out_b  (split out)
  mgemm_k<1, false, true, false><<<dim3(8, 32, 1), 256, 0, stream>>>(
      attno, 2048, 0, 0, 0, 1024,
      Wo, 2048, 0, 0, 0, 1024,
      nullptr, encf, 2048, 0, 0, 1024,
      1024, 1, aout_b, nullptr, 1, 1, 1.f);

  // G7: h1 = relu(encf @ tr_w1^T + tr_b1)  (fp32 out)
  mgemm_k<0, true, true, false><<<dim3(8, 32, 1), 256, 0, stream>>>(
      encf, 2048, 0, 0, 0, 1024,
      Wt, 2048, 0, 0, 0, 1024,
      h1, nullptr, 1024, 0, 0, 0,
      1024, 1, tr_b1, nullptr, 1, 1, 1.f);

  tr2_k<<<1024, 256, 0, stream>>>(h1, tr_w2, tr_b2, lgts);

  // zero dispatch+combine (wipes all arena scratch)
  fill0_k<<<4096, 256, 0, stream>>>((float4*)out, 25165824LL);

  router_k<<<16, 256, 0, stream>>>(out, parts);
  aux_k<<<1, 64, 0, stream>>>(parts, out);
}

// Round 5
// 481.443 us; speedup vs baseline: 2.7165x; 1.0959x over previous
//
#include <hip/hip_runtime.h>
#include <hip/hip_bf16.h>

// TimeMoERouter: B=8 S=512 H=1024 E=8 TOPK=2 NHEADS=8 DH=128 CAP=1536
// Round 5: A-only LDS staging (double-buffered, BK=32) + B operands in
// MFMA-fragment-native global layout (coalesced dwordx4 frag loads, 2-deep
// register ring). Cuts per-k-step LDS traffic ~2.4x (was the binding pipe).
// G3's epilogue emits K/V frag-native (vtrans_k deleted); weights converted
// straight to frag layout. d_out is the scratch arena; fill0 re-zeroes it.

#define Hh 1024

typedef __attribute__((ext_vector_type(8))) short short8v;
typedef __attribute__((ext_vector_type(4))) float f32x4;

static __device__ __forceinline__ ushort f2bf(float x) {
  uint u = __float_as_uint(x);
  u += 0x7FFF + ((u >> 16) & 1);          // round-to-nearest-even
  return (ushort)(u >> 16);
}
static __device__ __forceinline__ float bf2f(ushort h) {
  return __uint_as_float(((uint)h) << 16);
}

// ---------------- split-precision MFMA GEMM ----------------
// C[m,n] = alpha * sum_k A[m,k]*B[n,k], segments (Ah,Bh)+(Al,Bh)+(Ah,Bl).
// A: bf16, row stride lda, hi col aHi+k, lo col aLo+k (LDS-staged, dbuf).
// Bf: frag-native [hl][BNT ntiles][BKC kchunks][64 lanes][8 ush];
//     frag(hl,nt,kc) holds B[nt*16+(l&15)][kc*32+(l>>4)*8+j].
// EPI: 0 fp32 C; 1 split bf16 row-major (hi col n, lo col n+splitOff);
//      2 QKV: n0<1024 -> Q split row-major (Ch); <2048 -> Kf frags; else Vf.
// Tile 128x128, BK=32, 4 waves (2x2), 16x16x32 bf16 MFMA.
template<int EPI, bool RELU, bool HAS_BN, bool HAS_BSN>
__global__ __launch_bounds__(256, 2) void mgemm_k(
    const ushort* __restrict__ A, int lda, long long sAmaj, long long sAmin, int aHi, int aLo,
    const ushort* __restrict__ Bf, int BNT, int BKC, long long sBmaj, long long sBmin,
    float* __restrict__ Cf, ushort* __restrict__ Ch, int ldc, long long sCmaj, long long sCmin,
    int splitOff,
    ushort* __restrict__ pK, ushort* __restrict__ pV,
    int Kd, int zdiv,
    const float* __restrict__ bN, const float* __restrict__ bSN, int ldbs, int smod,
    float alpha)
{
  // XCD-aware bijective swizzle (all grids are multiples of 8)
  int gx = gridDim.x, gy = gridDim.y;
  int lin = (blockIdx.z * gy + blockIdx.y) * gx + blockIdx.x;
  int nwg = gx * gy * gridDim.z;
  int cpx = nwg >> 3;
  int swz = (lin & 7) * cpx + (lin >> 3);
  int bz = swz / (gx * gy);
  int rem = swz - bz * (gx * gy);
  int by = rem / gx, bx = rem - by * gx;

  int zj = bz / zdiv, zi = bz - zj * zdiv;
  A += (size_t)zj * sAmaj + (size_t)zi * sAmin;
  const ushort* bfb = Bf + (size_t)zj * sBmaj + (size_t)zi * sBmin;
  long long coff = (long long)zj * sCmaj + (long long)zi * sCmin;

  int m0 = by * 128, n0 = bx * 128;

  __shared__ __align__(16) ushort smem[16384];   // 32KB: 2 bufs x {Ah 8K, Al 8K}

  int t = threadIdx.x;
  int l = t & 63, w = t >> 6;
  int wm = w >> 1, wn = w & 1;

  f32x4 acc[4][4];
#pragma unroll
  for (int i = 0; i < 4; ++i)
#pragma unroll
    for (int j = 0; j < 4; ++j) acc[i][j] = (f32x4){0.f, 0.f, 0.f, 0.f};

  // A staging: thread covers row srow, int4-slots {sc,sc+1} of 4
  int srow = t >> 1;
  int sc = (t & 1) * 2;
  const ushort* gAh = A + (size_t)(m0 + srow) * lda + aHi + sc * 8;
  const ushort* gAl = A + (size_t)(m0 + srow) * lda + aLo + sc * 8;
  int wsw = ((srow >> 1) & 7) << 4;
  int wo0 = (srow * 64 + sc * 16) ^ wsw;
  int wo1 = wo0 ^ 16;

  // A fragment read offsets
  int aoff[4];
#pragma unroll
  for (int mi = 0; mi < 4; ++mi) {
    int row = wm * 64 + mi * 16 + (l & 15);
    aoff[mi] = (row * 64 + (l >> 4) * 16) ^ (((row >> 1) & 7) << 4);
  }

  // B frag pointers (per ni, hi and lo)
  const ushort* bph[4];
  const ushort* bpl[4];
  int ntg0 = (n0 >> 4) + wn * 4;
#pragma unroll
  for (int ni = 0; ni < 4; ++ni) {
    bph[ni] = bfb + ((size_t)(ntg0 + ni) * BKC) * 512 + l * 8;
    bpl[ni] = bfb + ((size_t)(BNT + ntg0 + ni) * BKC) * 512 + l * 8;
  }

  int4 a0h0, a0h1, a0l0, a0l1, a1h0, a1h1, a1l0, a1l1;
  short8v B0h[4], B0l[4], B1h[4], B1l[4];

#define LOADA0(s) { a0h0 = *(const int4*)(gAh + (s)*32); a0h1 = *(const int4*)(gAh + (s)*32 + 8); \
                    a0l0 = *(const int4*)(gAl + (s)*32); a0l1 = *(const int4*)(gAl + (s)*32 + 8); }
#define LOADA1(s) { a1h0 = *(const int4*)(gAh + (s)*32); a1h1 = *(const int4*)(gAh + (s)*32 + 8); \
                    a1l0 = *(const int4*)(gAl + (s)*32); a1l1 = *(const int4*)(gAl + (s)*32 + 8); }
#define STOREA(h0, h1, l0, l1, base) { char* nb = (char*)smem + (base); \
    *(int4*)(nb + wo0) = h0; *(int4*)(nb + wo1) = h1; \
    *(int4*)(nb + 8192 + wo0) = l0; *(int4*)(nb + 8192 + wo1) = l1; }
#define LOADB(BH, BL, s) { _Pragma("unroll") \
    for (int ni = 0; ni < 4; ++ni) { \
      BH[ni] = *(const short8v*)(bph[ni] + (size_t)(s) * 512); \
      BL[ni] = *(const short8v*)(bpl[ni] + (size_t)(s) * 512); } }
#define MFMA_STEP(ahb, alb, BH, BL) { \
    short8v ah[4], al[4]; \
    _Pragma("unroll") for (int mi = 0; mi < 4; ++mi) \
      ah[mi] = *(const short8v*)((char*)smem + (ahb) + aoff[mi]); \
    _Pragma("unroll") for (int mi = 0; mi < 4; ++mi) \
      al[mi] = *(const short8v*)((char*)smem + (alb) + aoff[mi]); \
    _Pragma("unroll") for (int ni = 0; ni < 4; ++ni) \
      _Pragma("unroll") for (int mi = 0; mi < 4; ++mi) \
        acc[mi][ni] = __builtin_amdgcn_mfma_f32_16x16x32_bf16(ah[mi], BH[ni], acc[mi][ni], 0, 0, 0); \
    _Pragma("unroll") for (int ni = 0; ni < 4; ++ni) \
      _Pragma("unroll") for (int mi = 0; mi < 4; ++mi) \
        acc[mi][ni] = __builtin_amdgcn_mfma_f32_16x16x32_bf16(al[mi], BH[ni], acc[mi][ni], 0, 0, 0); \
    _Pragma("unroll") for (int ni = 0; ni < 4; ++ni) \
      _Pragma("unroll") for (int mi = 0; mi < 4; ++mi) \
        acc[mi][ni] = __builtin_amdgcn_mfma_f32_16x16x32_bf16(ah[mi], BL[ni], acc[mi][ni], 0, 0, 0); }

  int nt = Kd >> 5;            // always even (>=4)
  LOADA0(0); LOADB(B0h, B0l, 0);
  LOADA1(1); LOADB(B1h, B1l, 1);
  STOREA(a0h0, a0h1, a0l0, a0l1, 0);
  __syncthreads();
  for (int s2 = 0; s2 < nt; s2 += 2) {
    if (s2 + 2 < nt) LOADA0(s2 + 2);
    MFMA_STEP(0, 8192, B0h, B0l);
    if (s2 + 2 < nt) LOADB(B0h, B0l, s2 + 2);
    STOREA(a1h0, a1h1, a1l0, a1l1, 16384);
    __syncthreads();
    if (s2 + 3 < nt) LOADA1(s2 + 3);
    MFMA_STEP(16384, 24576, B1h, B1l);
    if (s2 + 3 < nt) LOADB(B1h, B1l, s2 + 3);
    if (s2 + 2 < nt) STOREA(a0h0, a0h1, a0l0, a0l1, 0);
    __syncthreads();
  }
#undef LOADA0
#undef LOADA1
#undef STOREA
#undef LOADB
#undef MFMA_STEP

  // fold alpha + biases + relu into acc
#pragma unroll
  for (int mi = 0; mi < 4; ++mi)
#pragma unroll
    for (int j = 0; j < 4; ++j) {
      int m = m0 + wm * 64 + mi * 16 + (l >> 4) * 4 + j;
#pragma unroll
      for (int ni = 0; ni < 4; ++ni) {
        int n = n0 + wn * 64 + ni * 16 + (l & 15);
        float x = acc[mi][ni][j] * alpha;
        if (HAS_BN) x += bN[n];
        if (HAS_BSN) x += bSN[(size_t)(m % smod) * ldbs + n];
        if (RELU) x = fmaxf(x, 0.f);
        acc[mi][ni][j] = x;
      }
    }

  if (EPI == 0) {
    // fp32 LDS-bounce: two 64-row passes, coalesced int4 stores
    float* Fs = (float*)smem;
#pragma unroll
    for (int p = 0; p < 2; ++p) {
      __syncthreads();
      if (wm == p) {
#pragma unroll
        for (int mi = 0; mi < 4; ++mi)
#pragma unroll
          for (int j = 0; j < 4; ++j) {
            int r = mi * 16 + (l >> 4) * 4 + j;
#pragma unroll
            for (int ni = 0; ni < 4; ++ni) {
              int c = wn * 64 + ni * 16 + (l & 15);
              *(float*)((char*)Fs + ((r * 512 + c * 4) ^ ((r & 7) << 4))) = acc[mi][ni][j];
            }
          }
      }
      __syncthreads();
#pragma unroll
      for (int r8 = 0; r8 < 8; ++r8) {
        int idx = r8 * 256 + t;
        int row = idx >> 5, slot = idx & 31;
        int4 v = *(const int4*)((char*)Fs + ((row * 512 + slot * 16) ^ ((row & 7) << 4)));
        *(int4*)(Cf + coff + (size_t)(m0 + p * 64 + row) * ldc + n0 + slot * 4) = v;
      }
    }
  } else {
    __syncthreads();
    ushort* Es = smem;                     // [128][128] ushort = 32KB
    bool isQ = (EPI == 1) || (n0 < 1024);
    bool isK = (EPI == 2) && !isQ && (n0 < 2048);
    int bb = m0 >> 9, s0 = m0 & 511;
    int hh2 = isK ? ((n0 - 1024) >> 7) : ((n0 - 2048) >> 7);
    size_t kvb = (size_t)(bb * 8 + hh2) * 131072;
#pragma unroll
    for (int pass = 0; pass < 2; ++pass) {
      if (isQ) {
#pragma unroll
        for (int mi = 0; mi < 4; ++mi)
#pragma unroll
          for (int j = 0; j < 4; ++j) {
            int lr = wm * 64 + mi * 16 + (l >> 4) * 4 + j;
#pragma unroll
            for (int ni = 0; ni < 4; ++ni) {
              int lcb = (wn * 64 + ni * 16 + (l & 15)) * 2;
              float x = acc[mi][ni][j];
              ushort h = f2bf(x);
              ushort vv = (pass == 0) ? h : f2bf(x - bf2f(h));
              *(ushort*)((char*)Es + ((lr * 256 + lcb) ^ ((lr & 7) << 4))) = vv;
            }
          }
      } else if (isK) {
        // normal orientation (rows = m-local = s)
#pragma unroll
        for (int mi = 0; mi < 4; ++mi)
#pragma unroll
          for (int j = 0; j < 4; ++j) {
            int lr = wm * 64 + mi * 16 + (l >> 4) * 4 + j;
#pragma unroll
            for (int ni = 0; ni < 4; ++ni) {
              int lcb = (wn * 64 + ni * 16 + (l & 15)) * 2;
              float x = acc[mi][ni][j];
              ushort h = f2bf(x);
              ushort vv = (pass == 0) ? h : f2bf(x - bf2f(h));
              *(ushort*)((char*)Es + ((lr * 256 + lcb) ^ ((lr & 7) << 4))) = vv;
            }
          }
      } else {
        // V: transposed (rows = n-local = d, cols = m-local = s)
#pragma unroll
        for (int mi = 0; mi < 4; ++mi)
#pragma unroll
          for (int j = 0; j < 4; ++j) {
            int cc = (wm * 64 + mi * 16 + (l >> 4) * 4 + j) * 2;
#pragma unroll
            for (int ni = 0; ni < 4; ++ni) {
              int rr = wn * 64 + ni * 16 + (l & 15);
              float x = acc[mi][ni][j];
              ushort h = f2bf(x);
              ushort vv = (pass == 0) ? h : f2bf(x - bf2f(h));
              *(ushort*)((char*)Es + ((rr * 256 + cc) ^ ((rr & 7) << 4))) = vv;
            }
          }
      }
      __syncthreads();
      if (isQ) {
        int off = (pass == 0) ? 0 : splitOff;
#pragma unroll
        for (int r = 0; r < 8; ++r) {
          int idx = r * 256 + t;
          int row = idx >> 4, cb = (idx & 15) * 16;
          int4 v = *(const int4*)((char*)Es + ((row * 256 + cb) ^ ((row & 7) << 4)));
          *(int4*)((char*)(Ch + coff + (size_t)(m0 + row) * ldc + off + n0) + cb) = v;
        }
      } else if (isK) {
#pragma unroll
        for (int sw = 0; sw < 8; ++sw) {
          int idx = sw * 256 + t;
          int f = idx >> 6, l2 = idx & 63;
          int st = f >> 2, dc = f & 3;
          int row = st * 16 + (l2 & 15);
          int colB = (dc * 32 + ((l2 >> 4) << 3)) * 2;
          short8v v = *(const short8v*)((char*)Es + ((row * 256 + colB) ^ ((row & 7) << 4)));
          *(short8v*)(pK + kvb + (size_t)((pass * 32 + (s0 >> 4) + st) * 4 + dc) * 512 + l2 * 8) = v;
        }
      } else {
#pragma unroll
        for (int sw = 0; sw < 8; ++sw) {
          int idx = sw * 256 + t;
          int f = idx >> 6, l2 = idx & 63;
          int dt = f >> 2, sch = f & 3;
          int row = dt * 16 + (l2 & 15);
          int colB = (sch * 32 + ((l2 >> 4) << 3)) * 2;
          short8v v = *(const short8v*)((char*)Es + ((row * 256 + colB) ^ ((row & 7) << 4)));
          *(short8v*)(pV + kvb + (size_t)((pass * 8 + dt) * 16 + (s0 >> 5) + sch) * 512 + l2 * 8) = v;
        }
      }
      if (pass == 0) __syncthreads();
    }
  }
}

// ---------------- fp32 [N][K] -> frag-native hi|lo ----------------
// Wf[hl][NT][KC][64][8]: frag(hl,nt,kc) lane l elem j = W[nt*16+(l&15)][kc*32+(l>>4)*8+j]
__global__ __launch_bounds__(64) void convertf_k(
    const float* __restrict__ W, int ldw, ushort* __restrict__ Wf, int NT, int KC)
{
  int kc = blockIdx.x, nt2 = blockIdx.y, l = threadIdx.x;
  const float* src = W + (size_t)(nt2 * 16 + (l & 15)) * ldw + kc * 32 + ((l >> 4) << 3);
  ushort h8[8], l8[8];
#pragma unroll
  for (int j = 0; j < 8; ++j) {
    float x = src[j];
    h8[j] = f2bf(x);
    l8[j] = f2bf(x - bf2f(h8[j]));
  }
  *(int4*)(Wf + ((size_t)nt2 * KC + kc) * 512 + l * 8) = *(int4*)h8;
  *(int4*)(Wf + ((size_t)(NT + nt2) * KC + kc) * 512 + l * 8) = *(int4*)l8;
}

// ---------------- fp32 [N][K] -> bf16 hi|lo [N][2K] (row-major, for A) ----
__global__ __launch_bounds__(256) void convert_k(
    const float* __restrict__ W, int lda, ushort* __restrict__ Whl, int K)
{
  int r = blockIdx.x;
  int c = threadIdx.x * 4;
  const float* src = W + (size_t)r * lda + c;
  float x0 = src[0], x1 = src[1], x2 = src[2], x3 = src[3];
  ushort4 h, lo;
  h.x = f2bf(x0); lo.x = f2bf(x0 - bf2f(h.x));
  h.y = f2bf(x1); lo.y = f2bf(x1 - bf2f(h.y));
  h.z = f2bf(x2); lo.z = f2bf(x2 - bf2f(h.z));
  h.w = f2bf(x3); lo.w = f2bf(x3 - bf2f(h.w));
  ushort* dst = Whl + (size_t)r * 2 * K;
  *(ushort4*)&dst[c] = h;
  *(ushort4*)&dst[K + c] = lo;
}

// ---------------- seasonal / positional precompute (fp32) ----------------
__global__ __launch_bounds__(256) void precompute_k(
    const float* __restrict__ pos_emb,
    const float* __restrict__ se_w1, const float* __restrict__ se_b1,
    const float* __restrict__ se_w2, const float* __restrict__ se_b2,
    const float* __restrict__ sexp_w, const float* __restrict__ sexp_b,
    const float* __restrict__ te_w1, const float* __restrict__ te_b1,
    float* __restrict__ psea, float* __restrict__ bias1)
{
  int s = blockIdx.x, t = threadIdx.x;
  float ts = (float)s;
  float se = sinf(((ts * 2.0f) * 3.14159274101257324f) / 24.0f);
  __shared__ float l1[256], l2[256];
  l1[t] = fmaxf(se * se_w1[t] + se_b1[t], 0.f);
  __syncthreads();
  {
    float a = se_b2[t];
    const float* wr = se_w2 + (size_t)t * 256;
    for (int i = 0; i < 256; ++i) a += l1[i] * wr[i];
    l2[t] = a;
  }
  __syncthreads();
#pragma unroll
  for (int r = 0; r < 4; ++r) {
    int h = r * 256 + t;
    float v = sexp_b[h];
    const float* wr = sexp_w + (size_t)h * 256;
    for (int j = 0; j < 256; ++j) v += l2[j] * wr[j];
    psea[s * Hh + h] = pos_emb[s * Hh + h] + v;
    bias1[s * Hh + h] = te_b1[h] + ts * te_w1[(size_t)h * 1026 + 1024]
                                 + se * te_w1[(size_t)h * 1026 + 1025];
  }
}

// ---------------- softmax over score rows; writes split P in place --------
__global__ __launch_bounds__(256) void softmax2_k(float* __restrict__ S)
{
  int row = blockIdx.x * 4 + (threadIdx.x >> 6);
  int lane = threadIdx.x & 63;
  float* p = S + (size_t)row * 512;
  float4 a = *(float4*)&p[lane * 4];
  float4 b = *(float4*)&p[256 + lane * 4];
  float m = fmaxf(fmaxf(fmaxf(a.x, a.y), fmaxf(a.z, a.w)),
                  fmaxf(fmaxf(b.x, b.y), fmaxf(b.z, b.w)));
#pragma unroll
  for (int off = 32; off; off >>= 1) m = fmaxf(m, __shfl_xor(m, off));
  a.x = expf(a.x - m); a.y = expf(a.y - m); a.z = expf(a.z - m); a.w = expf(a.w - m);
  b.x = expf(b.x - m); b.y = expf(b.y - m); b.z = expf(b.z - m); b.w = expf(b.w - m);
  float s = a.x + a.y + a.z + a.w + b.x + b.y + b.z + b.w;
#pragma unroll
  for (int off = 32; off; off >>= 1) s += __shfl_xor(s, off);
  float inv = 1.f / s;
  a.x *= inv; a.y *= inv; a.z *= inv; a.w *= inv;
  b.x *= inv; b.y *= inv; b.z *= inv; b.w *= inv;
  ushort* u = (ushort*)S + (size_t)row * 1024;    // [hi 512 | lo 512]
  ushort4 ha, la, hb, lb;
  ha.x = f2bf(a.x); la.x = f2bf(a.x - bf2f(ha.x));
  ha.y = f2bf(a.y); la.y = f2bf(a.y - bf2f(ha.y));
  ha.z = f2bf(a.z); la.z = f2bf(a.z - bf2f(ha.z));
  ha.w = f2bf(a.w); la.w = f2bf(a.w - bf2f(ha.w));
  hb.x = f2bf(b.x); lb.x = f2bf(b.x - bf2f(hb.x));
  hb.y = f2bf(b.y); lb.y = f2bf(b.y - bf2f(hb.y));
  hb.z = f2bf(b.z); lb.z = f2bf(b.z - bf2f(hb.z));
  hb.w = f2bf(b.w); lb.w = f2bf(b.w - bf2f(hb.w));
  *(ushort4*)&u[lane * 4] = ha;
  *(ushort4*)&u[512 + lane * 4] = la;
  *(ushort4*)&u[256 + lane * 4] = hb;
  *(ushort4*)&u[768 + lane * 4] = lb;
}

// ---------------- logits = h1 @ tr_w2^T + b  (N=8, fp32 VALU) ----------
__global__ __launch_bounds__(256) void tr2_k(
    const float* __restrict__ h1, const float* __restrict__ w,
    const float* __restrict__ bias, float* __restrict__ logits)
{
  int wid = threadIdx.x >> 6, lane = threadIdx.x & 63;
  int t = blockIdx.x * 4 + wid;
  const float* x = h1 + (size_t)t * Hh;
  float acc[8];
#pragma unroll
  for (int e = 0; e < 8; ++e) acc[e] = 0.f;
  for (int k = lane; k < Hh; k += 64) {
    float xv = x[k];
#pragma unroll
    for (int e = 0; e < 8; ++e) acc[e] += xv * w[e * Hh + k];
  }
#pragma unroll
  for (int e = 0; e < 8; ++e) {
#pragma unroll
    for (int off = 32; off; off >>= 1) acc[e] += __shfl_xor(acc[e], off);
  }
  if (lane == 0) {
#pragma unroll
    for (int e = 0; e < 8; ++e) logits[(size_t)t * 8 + e] = acc[e] + bias[e];
  }
}

// ---------------- zero fill of dispatch+combine ----------------
__global__ __launch_bounds__(256) void fill0_k(float4* __restrict__ p, long long n4)
{
  long long i = (long long)blockIdx.x * 256 + threadIdx.x;
  long long stride = (long long)gridDim.x * 256;
  float4 z = make_float4(0.f, 0.f, 0.f, 0.f);
  for (; i < n4; i += stride) p[i] = z;
}

// ---------------- router: softmax, top2, slot writes, partial p-sums -------
__global__ __launch_bounds__(256) void router_k(
    float* __restrict__ out, float* __restrict__ partials)
{
  int t = blockIdx.x * 256 + threadIdx.x;            // token 0..4095
  float* lg = out + 100663296 + (size_t)t * 8;       // logits (in-place -> probs)
  float p[8];
#pragma unroll
  for (int e = 0; e < 8; ++e) p[e] = lg[e];
  float m = p[0];
#pragma unroll
  for (int e = 1; e < 8; ++e) m = fmaxf(m, p[e]);
  float s = 0.f;
#pragma unroll
  for (int e = 0; e < 8; ++e) { p[e] = expf(p[e] - m); s += p[e]; }
  float inv = 1.f / s;
#pragma unroll
  for (int e = 0; e < 8; ++e) p[e] *= inv;
#pragma unroll
  for (int e = 0; e < 8; ++e) lg[e] = p[e];          // router_probs out

  int i0 = 0; float v0 = p[0];
#pragma unroll
  for (int e = 1; e < 8; ++e) if (p[e] > v0) { v0 = p[e]; i0 = e; }
  int i1 = -1; float v1 = -1.f;
#pragma unroll
  for (int e = 0; e < 8; ++e) if (e != i0 && p[e] > v1) { v1 = p[e]; i1 = e; }
  float wn = 1.f / (v0 + v1);
  size_t db = (size_t)t * (8 * 1536);
  out[db + (size_t)i0 * 1536] = 1.f;
  out[db + (size_t)i1 * 1536] = 1.f;
  out[50331648 + db + (size_t)i0 * 1536] = v0 * wn;
  out[50331648 + db + (size_t)i1 * 1536] = v1 * wn;

  __shared__ float red[256];
#pragma unroll
  for (int e = 0; e < 8; ++e) {
    red[threadIdx.x] = p[e];
    __syncthreads();
    for (int st = 128; st; st >>= 1) {
      if (threadIdx.x < st) red[threadIdx.x] += red[threadIdx.x + st];
      __syncthreads();
    }
    if (threadIdx.x == 0) partials[blockIdx.x * 8 + e] = red[0];
    __syncthreads();
  }
}

// ---------------- aux loss + cleanup of partials scratch ----------------
__global__ __launch_bounds__(64) void aux_k(float* __restrict__ partials,
                                            float* __restrict__ out)
{
  int lane = threadIdx.x;
  float v = 0.f;
  if (lane < 8) {
    float s = 0.f;
    for (int b = 0; b < 16; ++b) s += partials[b * 8 + lane];
    float pm = s / 4096.f;
    v = pm * logf(pm * 8.f + 1e-9f);
  }
#pragma unroll
  for (int off = 4; off; off >>= 1) v += __shfl_xor(v, off);
  if (lane == 0) out[100696064] = v;
  partials[lane] = 0.f;
  partials[64 + lane] = 0.f;
}

extern "C" void kernel_launch(void* const* d_in, const int* in_sizes, int n_in,
                              void* d_out, int out_size, void* d_ws, size_t ws_size,
                              hipStream_t stream)
{
  const float* hidden = (const float*)d_in[0];
  const float* pos_emb = (const float*)d_in[1];
  const float* se_w1 = (const float*)d_in[2];
  const float* se_b1 = (const float*)d_in[3];
  const float* se_w2 = (const float*)d_in[4];
  const float* se_b2 = (const float*)d_in[5];
  const float* sexp_w = (const float*)d_in[6];
  const float* sexp_b = (const float*)d_in[7];
  const float* te_w1 = (const float*)d_in[8];
  const float* te_b1 = (const float*)d_in[9];
  const float* te_w2 = (const float*)d_in[10];
  const float* te_b2 = (const float*)d_in[11];
  const float* ain_w = (const float*)d_in[12];
  const float* ain_b = (const float*)d_in[13];
  const float* aout_w = (const float*)d_in[14];
  const float* aout_b = (const float*)d_in[15];
  const float* tr_w1 = (const float*)d_in[16];
  const float* tr_b1 = (const float*)d_in[17];
  const float* tr_w2 = (const float*)d_in[18];
  const float* tr_b2 = (const float*)d_in[19];
  float* out = (float*)d_out;

  // scratch arena: byte offsets inside d_out's dispatch+combine region (402MB)
  char* arena = (char*)d_out;
  ushort* W1f  = (ushort*)(arena + 0);          // [2][64][32][512]  4MB
  ushort* W2f  = (ushort*)(arena + 4194304);    // 4MB
  ushort* Waf  = (ushort*)(arena + 8388608);    // [2][192][32][512] 12MB
  ushort* Wof  = (ushort*)(arena + 20971520);   // 4MB
  ushort* Wtf  = (ushort*)(arena + 25165824);   // 4MB
  ushort* hid2 = (ushort*)(arena + 29360128);   // [4096][2048] 16MB
  ushort* enc1 = (ushort*)(arena + 46137344);   // 16MB
  ushort* enc2 = (ushort*)(arena + 62914560);   // 16MB
  ushort* qbuf = (ushort*)(arena + 79691776);   // [4096][2048] 16MB
  ushort* Kf   = (ushort*)(arena + 96468992);   // [64][2][32][4][512] 16MB
  ushort* Vf   = (ushort*)(arena + 113246208);  // [64][2][8][16][512] 16MB
  float*  scor = (float*)(arena + 130023424);   // [64][512][512] 64MB -> split P
  ushort* attno= (ushort*)(arena + 197132288);  // 16MB
  ushort* encf = (ushort*)(arena + 213909504);  // 16MB
  float*  h1   = (float*)(arena + 230686720);   // [4096][1024] 16MB
  float*  psea = (float*)(arena + 247463936);   // 2MB
  float*  bias1= (float*)(arena + 249561088);   // 2MB
  float*  parts= out + 51380224;                // [16][8], zeroed by aux_k
  float*  lgts = out + 100663296;               // logits -> probs region

  // weight / input expansions
  convertf_k<<<dim3(32, 64), 64, 0, stream>>>(te_w1, 1026, W1f, 64, 32);
  convertf_k<<<dim3(32, 64), 64, 0, stream>>>(te_w2, 1024, W2f, 64, 32);
  convertf_k<<<dim3(32, 192), 64, 0, stream>>>(ain_w, 1024, Waf, 192, 32);
  convertf_k<<<dim3(32, 64), 64, 0, stream>>>(aout_w, 1024, Wof, 64, 32);
  convertf_k<<<dim3(32, 64), 64, 0, stream>>>(tr_w1, 1024, Wtf, 64, 32);
  convert_k<<<4096, 256, 0, stream>>>(hidden, 1024, hid2, 1024);

  precompute_k<<<512, 256, 0, stream>>>(pos_emb, se_w1, se_b1, se_w2, se_b2,
                                        sexp_w, sexp_b, te_w1, te_b1, psea, bias1);

  // G1: enc1 = relu(hidden @ te_w1'^T + bias1[s])
  mgemm_k<1, true, false, true><<<dim3(8, 32, 1), 256, 0, stream>>>(
      hid2, 2048, 0, 0, 0, 1024,
      W1f, 64, 32, 0, 0,
      nullptr, enc1, 2048, 0, 0, 1024, nullptr, nullptr,
      1024, 1, nullptr, bias1, 1024, 512, 1.f);

  // G2: enc2 = enc1 @ te_w2^T + te_b2 + psea[s]
  mgemm_k<1, false, true, true><<<dim3(8, 32, 1), 256, 0, stream>>>(
      enc1, 2048, 0, 0, 0, 1024,
      W2f, 64, 32, 0, 0,
      nullptr, enc2, 2048, 0, 0, 1024, nullptr, nullptr,
      1024, 1, te_b2, psea, 1024, 512, 1.f);

  // G3: qkv = enc2 @ attn_in_w^T + attn_in_b; Q row-major, K/V frag-native
  mgemm_k<2, false, true, false><<<dim3(24, 32, 1), 256, 0, stream>>>(
      enc2, 2048, 0, 0, 0, 1024,
      Waf, 192, 32, 0, 0,
      nullptr, qbuf, 2048, 0, 0, 1024, Kf, Vf,
      1024, 1, ain_b, nullptr, 1, 1, 1.f);

  // G4: scores[b,h] = Q K^T / sqrt(128)  (fp32 out)
  mgemm_k<0, false, false, false><<<dim3(4, 4, 64), 256, 0, stream>>>(
      qbuf, 2048, 1048576, 128, 0, 1024,
      Kf, 32, 4, 1048576, 131072,
      scor, nullptr, 512, 2097152, 262144, 0, nullptr, nullptr,
      128, 8, nullptr, nullptr, 1, 1, 0.08838834764831845f);

  softmax2_k<<<8192, 256, 0, stream>>>(scor);

  // G5: attno[b,h] = P @ V  (A = split P, B = Vf frag-native)
  mgemm_k<1, false, false, false><<<dim3(1, 4, 64), 256, 0, stream>>>(
      (const ushort*)scor, 1024, 4194304, 524288, 0, 512,
      Vf, 8, 16, 1048576, 131072,
      nullptr, attno, 2048, 1048576, 128, 1024, nullptr, nullptr,
      512, 8, nullptr, nullptr, 1, 1, 1.f);

  // G6: encf = attno @ attn_out_w^T + attn_out_b
  mgemm_k<1, false, true, false><<<dim3(8, 32, 1), 256, 0, stream>>>(
      attno, 2048, 0, 0, 0, 1024,
      Wof, 64, 32, 0, 0,
      nullptr, encf, 2048, 0, 0, 1024, nullptr, nullptr,
      1024, 1, aout_b, nullptr, 1, 1, 1.f);

  // G7: h1 = relu(encf @ tr_w1^T + tr_b1)  (fp32 out)
  mgemm_k<0, true, true, false><<<dim3(8, 32, 1), 256, 0, stream>>>(
      encf, 2048, 0, 0, 0, 1024,
      Wtf, 64, 32, 0, 0,
      h1, nullptr, 1024, 0, 0, 0, nullptr, nullptr,
      1024, 1, tr_b1, nullptr, 1, 1, 1.f);

  tr2_k<<<1024, 256, 0, stream>>>(h1, tr_w2, tr_b2, lgts);

  // zero dispatch+combine (wipes all arena scratch)
  fill0_k<<<4096, 256, 0, stream>>>((float4*)out, 25165824LL);

  router_k<<<16, 256, 0, stream>>>(out, parts);
  aux_k<<<1, 64, 0, stream>>>(parts, out);
}